// Round 1
// baseline (989.944 us; speedup 1.0000x reference)
//
#include <hip/hip_runtime.h>
#include <hip/hip_bf16.h>
#include <math.h>

#define NN 20000
#define DD 64
#define HH 10
#define HDIM 640
#define NEG 0.2f
#define H1 1500

// ---------------- GEMM1: xl = x @ W_gat, fused a_src/a_dst ----------------
__global__ __launch_bounds__(256) void k_gemm1(
    const float* __restrict__ x, const float* __restrict__ Wg,
    const float* __restrict__ att_s, const float* __restrict__ att_d,
    float* __restrict__ xl, float* __restrict__ a_src, float* __restrict__ a_dst)
{
    __shared__ float xs[8][64];          // 8 node rows of x
    __shared__ float ls[2][8][HH];       // per-node per-head partial dots
    const int tid = threadIdx.x;
    const int n0 = blockIdx.x * 8;

    ((float*)xs)[tid]       = x[(size_t)n0 * DD + tid];
    ((float*)xs)[tid + 256] = x[(size_t)n0 * DD + tid + 256];
    if (tid < 160) ((float*)ls)[tid] = 0.f;
    __syncthreads();

    for (int c = tid; c < HDIM; c += 256) {
        float acc[8];
        #pragma unroll
        for (int i = 0; i < 8; ++i) acc[i] = 0.f;
        for (int k = 0; k < DD; k += 4) {
            const float w0 = Wg[(size_t)(k + 0) * HDIM + c];
            const float w1 = Wg[(size_t)(k + 1) * HDIM + c];
            const float w2 = Wg[(size_t)(k + 2) * HDIM + c];
            const float w3 = Wg[(size_t)(k + 3) * HDIM + c];
            #pragma unroll
            for (int i = 0; i < 8; ++i) {
                const float4 xv = *(const float4*)&xs[i][k];
                acc[i] = fmaf(xv.x, w0, fmaf(xv.y, w1, fmaf(xv.z, w2, fmaf(xv.w, w3, acc[i]))));
            }
        }
        const int h = c >> 6, d = c & 63;
        const float as = att_s[h * DD + d];
        const float ad = att_d[h * DD + d];
        #pragma unroll
        for (int i = 0; i < 8; ++i) {
            xl[(size_t)(n0 + i) * HDIM + c] = acc[i];
            atomicAdd(&ls[0][i][h], acc[i] * as);
            atomicAdd(&ls[1][i][h], acc[i] * ad);
        }
    }
    __syncthreads();
    if (tid < 80) {
        const int i = tid / HH, h = tid % HH;
        a_src[(size_t)(n0 + i) * HH + h] = ls[0][i][h];
        a_dst[(size_t)(n0 + i) * HH + h] = ls[1][i][h];
    }
}

// ---------------- CSR build ----------------
__global__ void k_count(const int* __restrict__ ei, int E, int* __restrict__ cnt)
{
    const int e = blockIdx.x * blockDim.x + threadIdx.x;
    if (e >= E + NN) return;
    const int d = (e < E) ? ei[E + e] : (e - E);
    atomicAdd(&cnt[d], 1);
}

__global__ __launch_bounds__(1024) void k_scan(const int* __restrict__ cnt,
                                               int* __restrict__ rowptr,
                                               float* __restrict__ dinv)
{
    __shared__ int sh[1024];
    const int t = threadIdx.x;
    const int CH = 20;                       // 1024*20 >= 20000
    const int base = t * CH;
    int loc[CH];
    int s = 0;
    #pragma unroll
    for (int i = 0; i < CH; ++i) {
        const int idx = base + i;
        const int c = (idx < NN) ? cnt[idx] : 0;
        loc[i] = s; s += c;
    }
    sh[t] = s; __syncthreads();
    for (int off = 1; off < 1024; off <<= 1) {
        const int v = (t >= off) ? sh[t - off] : 0;
        __syncthreads();
        sh[t] += v;
        __syncthreads();
    }
    const int prev = (t == 0) ? 0 : sh[t - 1];
    #pragma unroll
    for (int i = 0; i < CH; ++i) {
        const int idx = base + i;
        if (idx < NN) {
            rowptr[idx] = prev + loc[i];
            dinv[idx]   = rsqrtf((float)cnt[idx]);   // cnt >= 1 (self-loop)
        }
    }
    if (t == 1023) rowptr[NN] = sh[1023];
}

__global__ void k_fill(const int* __restrict__ ei, int E,
                       const int* __restrict__ rowptr,
                       int* __restrict__ cursor, int* __restrict__ csr)
{
    const int e = blockIdx.x * blockDim.x + threadIdx.x;
    if (e >= E + NN) return;
    int s, d;
    if (e < E) { s = ei[e]; d = ei[E + e]; } else { s = d = e - E; }
    const int pos = atomicAdd(&cursor[d], 1);
    csr[rowptr[d] + pos] = s;
}

// ---------------- per-(node,head) online softmax stats ----------------
__global__ void k_stat(const int* __restrict__ rowptr, const int* __restrict__ csr,
                       const float* __restrict__ a_src, const float* __restrict__ a_dst,
                       float* __restrict__ mbuf, float* __restrict__ dbuf)
{
    const int g = blockIdx.x * blockDim.x + threadIdx.x;
    if (g >= NN * HH) return;
    const int n = g / HH, h = g - n * HH;
    const float adn = a_dst[g];
    const int j0 = rowptr[n], j1 = rowptr[n + 1];
    float mx = -INFINITY, dn = 0.f;
    for (int j = j0; j < j1; ++j) {
        const int s = csr[j];
        float av = a_src[s * HH + h] + adn;
        av = (av >= 0.f) ? av : NEG * av;
        if (av > mx) { dn = dn * __expf(mx - av) + 1.f; mx = av; }
        else         { dn += __expf(av - mx); }
    }
    mbuf[g] = mx; dbuf[g] = dn;
}

// ---------------- GAT gather: x1 = relu(segsum(w*xl[src]) + b_gat) ----------------
__global__ __launch_bounds__(320) void k_gat_gather(
    const int* __restrict__ rowptr, const int* __restrict__ csr,
    const float* __restrict__ a_src, const float* __restrict__ a_dst,
    const float* __restrict__ mbuf, const float* __restrict__ dbuf,
    const float* __restrict__ xl, const float* __restrict__ b_gat,
    float* __restrict__ x1)
{
    const int n = blockIdx.x, tid = threadIdx.x;
    const int c0 = tid, c1 = tid + 320;
    const int h0 = c0 >> 6, h1 = c1 >> 6;
    const float ad0 = a_dst[n * HH + h0], ad1 = a_dst[n * HH + h1];
    const float m0 = mbuf[n * HH + h0],   m1 = mbuf[n * HH + h1];
    const float r0 = 1.f / (dbuf[n * HH + h0] + 1e-16f);
    const float r1 = 1.f / (dbuf[n * HH + h1] + 1e-16f);
    float acc0 = 0.f, acc1 = 0.f;
    const int j0 = rowptr[n], j1 = rowptr[n + 1];
    for (int j = j0; j < j1; ++j) {
        const int s = csr[j];
        const float* xr = xl + (size_t)s * HDIM;
        float av0 = a_src[s * HH + h0] + ad0; av0 = (av0 >= 0.f) ? av0 : NEG * av0;
        float av1 = a_src[s * HH + h1] + ad1; av1 = (av1 >= 0.f) ? av1 : NEG * av1;
        const float w0 = __expf(av0 - m0) * r0;
        const float w1 = __expf(av1 - m1) * r1;
        acc0 = fmaf(w0, xr[c0], acc0);
        acc1 = fmaf(w1, xr[c1], acc1);
    }
    float v0 = acc0 + b_gat[c0];
    float v1 = acc1 + b_gat[c1];
    x1[(size_t)n * HDIM + c0] = (v0 > 0.f) ? v0 : 0.f;
    x1[(size_t)n * HDIM + c1] = (v1 > 0.f) ? v1 : 0.f;
}

// ---------------- GEMM2: xw = x1 @ W_gcn (fp32 tiled) ----------------
__global__ __launch_bounds__(256) void k_gemm2(const float* __restrict__ X,
                                               const float* __restrict__ W,
                                               float* __restrict__ Y)
{
    __shared__ float xsT[32][132];   // transposed A tile, padded (+4 keeps 16B align)
    __shared__ float wsb[32][64];
    const int tid = threadIdx.x;
    const int m0 = blockIdx.x * 128;
    const int n0 = blockIdx.y * 64;
    const int cid = tid & 15, rid = tid >> 4;
    const int r0 = rid * 8, cg = cid * 4;
    float acc[8][4];
    #pragma unroll
    for (int i = 0; i < 8; ++i)
        #pragma unroll
        for (int j = 0; j < 4; ++j) acc[i][j] = 0.f;

    for (int kb = 0; kb < HDIM; kb += 32) {
        #pragma unroll
        for (int j = 0; j < 4; ++j) {
            const int lin = tid + j * 256;           // 0..1023
            const int mm = lin >> 3, k4 = (lin & 7) * 4;
            float4 v = {0.f, 0.f, 0.f, 0.f};
            const int row = m0 + mm;
            if (row < NN) v = *(const float4*)&X[(size_t)row * HDIM + kb + k4];
            xsT[k4 + 0][mm] = v.x; xsT[k4 + 1][mm] = v.y;
            xsT[k4 + 2][mm] = v.z; xsT[k4 + 3][mm] = v.w;
        }
        #pragma unroll
        for (int j = 0; j < 2; ++j) {
            const int lin = tid + j * 256;           // 0..511
            const int kk = lin >> 4, n4 = (lin & 15) * 4;
            *(float4*)&wsb[kk][n4] = *(const float4*)&W[(size_t)(kb + kk) * HDIM + n0 + n4];
        }
        __syncthreads();
        #pragma unroll
        for (int k = 0; k < 32; ++k) {
            const float4 a0 = *(const float4*)&xsT[k][r0];
            const float4 a1 = *(const float4*)&xsT[k][r0 + 4];
            const float4 b  = *(const float4*)&wsb[k][cg];
            const float av[8] = {a0.x, a0.y, a0.z, a0.w, a1.x, a1.y, a1.z, a1.w};
            const float bv[4] = {b.x, b.y, b.z, b.w};
            #pragma unroll
            for (int i = 0; i < 8; ++i)
                #pragma unroll
                for (int j = 0; j < 4; ++j)
                    acc[i][j] = fmaf(av[i], bv[j], acc[i][j]);
        }
        __syncthreads();
    }
    #pragma unroll
    for (int i = 0; i < 8; ++i) {
        const int row = m0 + r0 + i;
        if (row < NN) {
            const float4 o = {acc[i][0], acc[i][1], acc[i][2], acc[i][3]};
            *(float4*)&Y[(size_t)row * HDIM + n0 + cg] = o;
        }
    }
}

// ---------------- GCN gather: x2 = relu(segsum(norm*xw[src]) + b_gcn) ----------------
__global__ __launch_bounds__(320) void k_gcn_gather(
    const int* __restrict__ rowptr, const int* __restrict__ csr,
    const float* __restrict__ dinv, const float* __restrict__ xw,
    const float* __restrict__ b_gcn, float* __restrict__ x2)
{
    const int n = blockIdx.x, tid = threadIdx.x;
    const int c0 = tid, c1 = tid + 320;
    const float dn = dinv[n];
    float acc0 = 0.f, acc1 = 0.f;
    const int j0 = rowptr[n], j1 = rowptr[n + 1];
    for (int j = j0; j < j1; ++j) {
        const int s = csr[j];
        const float wt = dinv[s] * dn;
        const float* xr = xw + (size_t)s * HDIM;
        acc0 = fmaf(wt, xr[c0], acc0);
        acc1 = fmaf(wt, xr[c1], acc1);
    }
    float v0 = acc0 + b_gcn[c0];
    float v1 = acc1 + b_gcn[c1];
    x2[(size_t)n * HDIM + c0] = (v0 > 0.f) ? v0 : 0.f;
    x2[(size_t)n * HDIM + c1] = (v1 > 0.f) ? v1 : 0.f;
}

// ---------------- pooling: col-wise max + sum (relu => nonneg => int atomicMax ok) ----------------
__global__ __launch_bounds__(64) void k_pool(const float* __restrict__ x2,
                                             float* __restrict__ pmax,
                                             float* __restrict__ psum)
{
    const int col = blockIdx.x * 64 + threadIdx.x;  // blockIdx.x in [0,10)
    const int nb = blockIdx.y;                      // [0,80)
    float mx = 0.f, sm = 0.f;
    const int nend = nb * 250 + 250;
    for (int n = nb * 250; n < nend; ++n) {
        const float v = x2[(size_t)n * HDIM + col];
        mx = fmaxf(mx, v); sm += v;
    }
    atomicMax((int*)&pmax[col], __float_as_int(mx));
    atomicAdd(&psum[col], sm);
}

// ---------------- MLP layer 1 (split-K into hacc) ----------------
__global__ __launch_bounds__(256) void k_mlp1(const float* __restrict__ pmax,
                                              const float* __restrict__ psum,
                                              const float* __restrict__ W1,
                                              float* __restrict__ hacc)
{
    __shared__ float pl[80];
    const int t = threadIdx.x;
    const int i0 = blockIdx.y * 80;
    if (t < 80) {
        const int i = i0 + t;
        pl[t] = (i < HDIM) ? pmax[i] : psum[i - HDIM] * (1.0f / NN);
    }
    __syncthreads();
    const int j = blockIdx.x * 256 + t;
    if (j >= H1) return;
    float acc = 0.f;
    #pragma unroll 8
    for (int i = 0; i < 80; ++i)
        acc = fmaf(pl[i], W1[(size_t)(i0 + i) * H1 + j], acc);
    atomicAdd(&hacc[j], acc);
}

// ---------------- MLP layer 2 ----------------
__global__ __launch_bounds__(256) void k_mlp2(const float* __restrict__ hacc,
                                              const float* __restrict__ b1,
                                              const float* __restrict__ W2,
                                              const float* __restrict__ b2,
                                              float* __restrict__ out)
{
    __shared__ float hsh[H1];
    __shared__ float red[256];
    const int t = threadIdx.x;
    for (int i = t; i < H1; i += 256) {
        const float v = hacc[i] + b1[i];
        hsh[i] = (v > 0.f) ? v : 0.f;
    }
    __syncthreads();
    float acc[10];
    #pragma unroll
    for (int k = 0; k < 10; ++k) acc[k] = 0.f;
    for (int i = t; i < H1; i += 256) {
        const float h = hsh[i];
        #pragma unroll
        for (int k = 0; k < 10; ++k) acc[k] = fmaf(h, W2[i * 10 + k], acc[k]);
    }
    for (int k = 0; k < 10; ++k) {
        red[t] = acc[k]; __syncthreads();
        for (int s2 = 128; s2 > 0; s2 >>= 1) {
            if (t < s2) red[t] += red[t + s2];
            __syncthreads();
        }
        if (t == 0) out[k] = red[0] + b2[k];
        __syncthreads();
    }
}

// ---------------- launch ----------------
extern "C" void kernel_launch(void* const* d_in, const int* in_sizes, int n_in,
                              void* d_out, int out_size, void* d_ws, size_t ws_size,
                              hipStream_t stream)
{
    const float* x     = (const float*)d_in[0];
    const float* Wg    = (const float*)d_in[1];
    const float* att_s = (const float*)d_in[2];
    const float* att_d = (const float*)d_in[3];
    const float* b_gat = (const float*)d_in[4];
    const float* Wgcn  = (const float*)d_in[5];
    const float* b_gcn = (const float*)d_in[6];
    const float* W1    = (const float*)d_in[7];
    const float* b1    = (const float*)d_in[8];
    const float* W2    = (const float*)d_in[9];
    const float* b2    = (const float*)d_in[10];
    const int*   ei    = (const int*)d_in[11];
    const int E = in_sizes[11] / 2;
    float* out = (float*)d_out;

    char* wsp = (char*)d_ws;
    size_t off = 0;
    auto alc = [&](size_t b) { void* p = wsp + off; off += (b + 255) & ~(size_t)255; return p; };
    float* bufA   = (float*)alc((size_t)NN * HDIM * 4);   // xl, later xw
    float* bufB   = (float*)alc((size_t)NN * HDIM * 4);   // x1, later x2
    float* aS     = (float*)alc((size_t)NN * HH * 4);
    float* aD     = (float*)alc((size_t)NN * HH * 4);
    float* mB     = (float*)alc((size_t)NN * HH * 4);
    float* dB     = (float*)alc((size_t)NN * HH * 4);
    int*   rowptr = (int*)alc((size_t)(NN + 1) * 4);
    int*   cnt    = (int*)alc((size_t)NN * 4);
    int*   cursor = (int*)alc((size_t)NN * 4);
    int*   csr    = (int*)alc((size_t)(E + NN) * 4);
    float* dinv   = (float*)alc((size_t)NN * 4);
    float* pmax   = (float*)alc((size_t)HDIM * 4);
    float* psum   = (float*)alc((size_t)HDIM * 4);
    float* hacc   = (float*)alc((size_t)H1 * 4);

    hipMemsetAsync(cnt,    0, (size_t)NN * 4,   stream);
    hipMemsetAsync(cursor, 0, (size_t)NN * 4,   stream);
    hipMemsetAsync(pmax,   0, (size_t)HDIM * 4, stream);
    hipMemsetAsync(psum,   0, (size_t)HDIM * 4, stream);
    hipMemsetAsync(hacc,   0, (size_t)H1 * 4,   stream);

    const int EP = E + NN;
    k_count<<<(EP + 255) / 256, 256, 0, stream>>>(ei, E, cnt);
    k_scan<<<1, 1024, 0, stream>>>(cnt, rowptr, dinv);
    k_fill<<<(EP + 255) / 256, 256, 0, stream>>>(ei, E, rowptr, cursor, csr);
    k_gemm1<<<NN / 8, 256, 0, stream>>>(x, Wg, att_s, att_d, bufA, aS, aD);
    k_stat<<<(NN * HH + 255) / 256, 256, 0, stream>>>(rowptr, csr, aS, aD, mB, dB);
    k_gat_gather<<<NN, 320, 0, stream>>>(rowptr, csr, aS, aD, mB, dB, bufA, b_gat, bufB);
    dim3 g2((NN + 127) / 128, HDIM / 64);
    k_gemm2<<<g2, 256, 0, stream>>>(bufB, Wgcn, bufA);
    k_gcn_gather<<<NN, 320, 0, stream>>>(rowptr, csr, dinv, bufA, b_gcn, bufB);
    dim3 gp(HDIM / 64, 80);
    k_pool<<<gp, 64, 0, stream>>>(bufB, pmax, psum);
    dim3 gm1(6, 16);
    k_mlp1<<<gm1, 256, 0, stream>>>(pmax, psum, W1, hacc);
    k_mlp2<<<1, 256, 0, stream>>>(hacc, b1, W2, b2, out);
}

// Round 2
// 745.263 us; speedup vs baseline: 1.3283x; 1.3283x over previous
//
#include <hip/hip_runtime.h>
#include <hip/hip_bf16.h>
#include <math.h>

#define NN 20000
#define DD 64
#define HH 10
#define HDIM 640
#define NEG 0.2f
#define H1 1500

// ---------------- GEMM1: xl = x @ W_gat, fused a_src/a_dst via shuffle ----------------
// M-tile 128, N-tile 64 (= exactly one head), K = 64 (whole depth, staged once).
__global__ __launch_bounds__(256) void k_gemm1(
    const float* __restrict__ x, const float* __restrict__ Wg,
    const float* __restrict__ att_s, const float* __restrict__ att_d,
    float* __restrict__ xl, float* __restrict__ a_src, float* __restrict__ a_dst)
{
    __shared__ float xsT[64][132];   // [k][m], padded
    __shared__ float wsb[64][64];    // [k][n]
    const int tid = threadIdx.x;
    const int m0 = blockIdx.x * 128;
    const int h  = blockIdx.y;       // one head per n-tile
    const int n0 = h * 64;

    // stage x tile: 128 rows x 64 k = 2048 float4
    #pragma unroll
    for (int j = 0; j < 8; ++j) {
        const int lin = tid + j * 256;
        const int mm = lin >> 4, k4 = (lin & 15) * 4;
        float4 v = {0.f, 0.f, 0.f, 0.f};
        const int row = m0 + mm;
        if (row < NN) v = *(const float4*)&x[(size_t)row * DD + k4];
        xsT[k4 + 0][mm] = v.x; xsT[k4 + 1][mm] = v.y;
        xsT[k4 + 2][mm] = v.z; xsT[k4 + 3][mm] = v.w;
    }
    // stage W tile: 64 k x 64 n = 1024 float4
    #pragma unroll
    for (int j = 0; j < 4; ++j) {
        const int lin = tid + j * 256;
        const int kk = lin >> 4, n4 = (lin & 15) * 4;
        *(float4*)&wsb[kk][n4] = *(const float4*)&Wg[(size_t)kk * HDIM + n0 + n4];
    }
    __syncthreads();

    const int cid = tid & 15, rid = tid >> 4;
    const int r0 = rid * 8, cg = cid * 4;
    float acc[8][4];
    #pragma unroll
    for (int i = 0; i < 8; ++i)
        #pragma unroll
        for (int j = 0; j < 4; ++j) acc[i][j] = 0.f;

    #pragma unroll 16
    for (int k = 0; k < 64; ++k) {
        const float4 a0 = *(const float4*)&xsT[k][r0];
        const float4 a1 = *(const float4*)&xsT[k][r0 + 4];
        const float4 b  = *(const float4*)&wsb[k][cg];
        const float av[8] = {a0.x, a0.y, a0.z, a0.w, a1.x, a1.y, a1.z, a1.w};
        const float bv[4] = {b.x, b.y, b.z, b.w};
        #pragma unroll
        for (int i = 0; i < 8; ++i)
            #pragma unroll
            for (int j = 0; j < 4; ++j)
                acc[i][j] = fmaf(av[i], bv[j], acc[i][j]);
    }

    // epilogue: write xl, reduce att dots across the 16 lanes of each row group
    const float4 as4 = *(const float4*)&att_s[h * DD + cg];
    const float4 ad4 = *(const float4*)&att_d[h * DD + cg];
    #pragma unroll
    for (int i = 0; i < 8; ++i) {
        const int row = m0 + r0 + i;
        float ps = acc[i][0] * as4.x + acc[i][1] * as4.y + acc[i][2] * as4.z + acc[i][3] * as4.w;
        float pd = acc[i][0] * ad4.x + acc[i][1] * ad4.y + acc[i][2] * ad4.z + acc[i][3] * ad4.w;
        #pragma unroll
        for (int off = 8; off > 0; off >>= 1) {
            ps += __shfl_down(ps, off, 16);
            pd += __shfl_down(pd, off, 16);
        }
        if (row < NN) {
            const float4 o = {acc[i][0], acc[i][1], acc[i][2], acc[i][3]};
            *(float4*)&xl[(size_t)row * HDIM + n0 + cg] = o;
            if (cid == 0) {
                a_src[row * HH + h] = ps;
                a_dst[row * HH + h] = pd;
            }
        }
    }
}

// ---------------- CSR build ----------------
__global__ void k_count(const int* __restrict__ ei, int E, int* __restrict__ cnt)
{
    const int e = blockIdx.x * blockDim.x + threadIdx.x;
    if (e >= E + NN) return;
    const int d = (e < E) ? ei[E + e] : (e - E);
    atomicAdd(&cnt[d], 1);
}

__global__ __launch_bounds__(1024) void k_scan(const int* __restrict__ cnt,
                                               int* __restrict__ rowptr,
                                               float* __restrict__ dinv)
{
    __shared__ int sh[1024];
    const int t = threadIdx.x;
    const int CH = 20;
    const int base = t * CH;
    int loc[CH];
    int s = 0;
    #pragma unroll
    for (int i = 0; i < CH; ++i) {
        const int idx = base + i;
        const int c = (idx < NN) ? cnt[idx] : 0;
        loc[i] = s; s += c;
    }
    sh[t] = s; __syncthreads();
    for (int off = 1; off < 1024; off <<= 1) {
        const int v = (t >= off) ? sh[t - off] : 0;
        __syncthreads();
        sh[t] += v;
        __syncthreads();
    }
    const int prev = (t == 0) ? 0 : sh[t - 1];
    #pragma unroll
    for (int i = 0; i < CH; ++i) {
        const int idx = base + i;
        if (idx < NN) {
            rowptr[idx] = prev + loc[i];
            dinv[idx]   = rsqrtf((float)cnt[idx]);
        }
    }
    if (t == 1023) rowptr[NN] = sh[1023];
}

__global__ void k_fill(const int* __restrict__ ei, int E,
                       const int* __restrict__ rowptr,
                       int* __restrict__ cursor, int* __restrict__ csr)
{
    const int e = blockIdx.x * blockDim.x + threadIdx.x;
    if (e >= E + NN) return;
    int s, d;
    if (e < E) { s = ei[e]; d = ei[E + e]; } else { s = d = e - E; }
    const int pos = atomicAdd(&cursor[d], 1);
    csr[rowptr[d] + pos] = s;
}

// ---------------- per-(node,head) online softmax stats ----------------
__global__ void k_stat(const int* __restrict__ rowptr, const int* __restrict__ csr,
                       const float* __restrict__ a_src, const float* __restrict__ a_dst,
                       float* __restrict__ mbuf, float* __restrict__ dbuf)
{
    const int g = blockIdx.x * blockDim.x + threadIdx.x;
    if (g >= NN * HH) return;
    const int n = g / HH, h = g - n * HH;
    const float adn = a_dst[g];
    const int j0 = rowptr[n], j1 = rowptr[n + 1];
    float mx = -INFINITY, dn = 0.f;
    for (int j = j0; j < j1; ++j) {
        const int s = csr[j];
        float av = a_src[s * HH + h] + adn;
        av = (av >= 0.f) ? av : NEG * av;
        if (av > mx) { dn = dn * __expf(mx - av) + 1.f; mx = av; }
        else         { dn += __expf(av - mx); }
    }
    mbuf[g] = mx; dbuf[g] = dn;
}

// ---------------- GAT gather: x1 = relu(segsum(w*xl[src]) + b_gat) ----------------
__global__ __launch_bounds__(320) void k_gat_gather(
    const int* __restrict__ rowptr, const int* __restrict__ csr,
    const float* __restrict__ a_src, const float* __restrict__ a_dst,
    const float* __restrict__ mbuf, const float* __restrict__ dbuf,
    const float* __restrict__ xl, const float* __restrict__ b_gat,
    float* __restrict__ x1)
{
    const int n = blockIdx.x, tid = threadIdx.x;
    const int c0 = tid, c1 = tid + 320;
    const int h0 = c0 >> 6, h1 = c1 >> 6;
    const float ad0 = a_dst[n * HH + h0], ad1 = a_dst[n * HH + h1];
    const float m0 = mbuf[n * HH + h0],   m1 = mbuf[n * HH + h1];
    const float r0 = 1.f / (dbuf[n * HH + h0] + 1e-16f);
    const float r1 = 1.f / (dbuf[n * HH + h1] + 1e-16f);
    float acc0 = 0.f, acc1 = 0.f;
    const int j0 = rowptr[n], j1 = rowptr[n + 1];
    for (int j = j0; j < j1; ++j) {
        const int s = csr[j];
        const float* xr = xl + (size_t)s * HDIM;
        float av0 = a_src[s * HH + h0] + ad0; av0 = (av0 >= 0.f) ? av0 : NEG * av0;
        float av1 = a_src[s * HH + h1] + ad1; av1 = (av1 >= 0.f) ? av1 : NEG * av1;
        const float w0 = __expf(av0 - m0) * r0;
        const float w1 = __expf(av1 - m1) * r1;
        acc0 = fmaf(w0, xr[c0], acc0);
        acc1 = fmaf(w1, xr[c1], acc1);
    }
    float v0 = acc0 + b_gat[c0];
    float v1 = acc1 + b_gat[c1];
    x1[(size_t)n * HDIM + c0] = (v0 > 0.f) ? v0 : 0.f;
    x1[(size_t)n * HDIM + c1] = (v1 > 0.f) ? v1 : 0.f;
}

// ---------------- GEMM2: xw = x1 @ W_gcn (fp32 tiled) ----------------
__global__ __launch_bounds__(256) void k_gemm2(const float* __restrict__ X,
                                               const float* __restrict__ W,
                                               float* __restrict__ Y)
{
    __shared__ float xsT[32][132];
    __shared__ float wsb[32][64];
    const int tid = threadIdx.x;
    const int m0 = blockIdx.x * 128;
    const int n0 = blockIdx.y * 64;
    const int cid = tid & 15, rid = tid >> 4;
    const int r0 = rid * 8, cg = cid * 4;
    float acc[8][4];
    #pragma unroll
    for (int i = 0; i < 8; ++i)
        #pragma unroll
        for (int j = 0; j < 4; ++j) acc[i][j] = 0.f;

    for (int kb = 0; kb < HDIM; kb += 32) {
        #pragma unroll
        for (int j = 0; j < 4; ++j) {
            const int lin = tid + j * 256;
            const int mm = lin >> 3, k4 = (lin & 7) * 4;
            float4 v = {0.f, 0.f, 0.f, 0.f};
            const int row = m0 + mm;
            if (row < NN) v = *(const float4*)&X[(size_t)row * HDIM + kb + k4];
            xsT[k4 + 0][mm] = v.x; xsT[k4 + 1][mm] = v.y;
            xsT[k4 + 2][mm] = v.z; xsT[k4 + 3][mm] = v.w;
        }
        #pragma unroll
        for (int j = 0; j < 2; ++j) {
            const int lin = tid + j * 256;
            const int kk = lin >> 4, n4 = (lin & 15) * 4;
            *(float4*)&wsb[kk][n4] = *(const float4*)&W[(size_t)(kb + kk) * HDIM + n0 + n4];
        }
        __syncthreads();
        #pragma unroll
        for (int k = 0; k < 32; ++k) {
            const float4 a0 = *(const float4*)&xsT[k][r0];
            const float4 a1 = *(const float4*)&xsT[k][r0 + 4];
            const float4 b  = *(const float4*)&wsb[k][cg];
            const float av[8] = {a0.x, a0.y, a0.z, a0.w, a1.x, a1.y, a1.z, a1.w};
            const float bv[4] = {b.x, b.y, b.z, b.w};
            #pragma unroll
            for (int i = 0; i < 8; ++i)
                #pragma unroll
                for (int j = 0; j < 4; ++j)
                    acc[i][j] = fmaf(av[i], bv[j], acc[i][j]);
        }
        __syncthreads();
    }
    #pragma unroll
    for (int i = 0; i < 8; ++i) {
        const int row = m0 + r0 + i;
        if (row < NN) {
            const float4 o = {acc[i][0], acc[i][1], acc[i][2], acc[i][3]};
            *(float4*)&Y[(size_t)row * HDIM + n0 + cg] = o;
        }
    }
}

// ---------------- GCN gather: x2 = relu(segsum(norm*xw[src]) + b_gcn) ----------------
__global__ __launch_bounds__(320) void k_gcn_gather(
    const int* __restrict__ rowptr, const int* __restrict__ csr,
    const float* __restrict__ dinv, const float* __restrict__ xw,
    const float* __restrict__ b_gcn, float* __restrict__ x2)
{
    const int n = blockIdx.x, tid = threadIdx.x;
    const int c0 = tid, c1 = tid + 320;
    const float dn = dinv[n];
    float acc0 = 0.f, acc1 = 0.f;
    const int j0 = rowptr[n], j1 = rowptr[n + 1];
    for (int j = j0; j < j1; ++j) {
        const int s = csr[j];
        const float wt = dinv[s] * dn;
        const float* xr = xw + (size_t)s * HDIM;
        acc0 = fmaf(wt, xr[c0], acc0);
        acc1 = fmaf(wt, xr[c1], acc1);
    }
    float v0 = acc0 + b_gcn[c0];
    float v1 = acc1 + b_gcn[c1];
    x2[(size_t)n * HDIM + c0] = (v0 > 0.f) ? v0 : 0.f;
    x2[(size_t)n * HDIM + c1] = (v1 > 0.f) ? v1 : 0.f;
}

// ---------------- pooling ----------------
__global__ __launch_bounds__(64) void k_pool(const float* __restrict__ x2,
                                             float* __restrict__ pmax,
                                             float* __restrict__ psum)
{
    const int col = blockIdx.x * 64 + threadIdx.x;
    const int nb = blockIdx.y;
    float mx = 0.f, sm = 0.f;
    const int nend = nb * 250 + 250;
    for (int n = nb * 250; n < nend; ++n) {
        const float v = x2[(size_t)n * HDIM + col];
        mx = fmaxf(mx, v); sm += v;
    }
    atomicMax((int*)&pmax[col], __float_as_int(mx));
    atomicAdd(&psum[col], sm);
}

// ---------------- MLP layer 1 (split-K into hacc) ----------------
__global__ __launch_bounds__(256) void k_mlp1(const float* __restrict__ pmax,
                                              const float* __restrict__ psum,
                                              const float* __restrict__ W1,
                                              float* __restrict__ hacc)
{
    __shared__ float pl[80];
    const int t = threadIdx.x;
    const int i0 = blockIdx.y * 80;
    if (t < 80) {
        const int i = i0 + t;
        pl[t] = (i < HDIM) ? pmax[i] : psum[i - HDIM] * (1.0f / NN);
    }
    __syncthreads();
    const int j = blockIdx.x * 256 + t;
    if (j >= H1) return;
    float acc = 0.f;
    #pragma unroll 8
    for (int i = 0; i < 80; ++i)
        acc = fmaf(pl[i], W1[(size_t)(i0 + i) * H1 + j], acc);
    atomicAdd(&hacc[j], acc);
}

// ---------------- MLP layer 2 ----------------
__global__ __launch_bounds__(256) void k_mlp2(const float* __restrict__ hacc,
                                              const float* __restrict__ b1,
                                              const float* __restrict__ W2,
                                              const float* __restrict__ b2,
                                              float* __restrict__ out)
{
    __shared__ float hsh[H1];
    __shared__ float red[256];
    const int t = threadIdx.x;
    for (int i = t; i < H1; i += 256) {
        const float v = hacc[i] + b1[i];
        hsh[i] = (v > 0.f) ? v : 0.f;
    }
    __syncthreads();
    float acc[10];
    #pragma unroll
    for (int k = 0; k < 10; ++k) acc[k] = 0.f;
    for (int i = t; i < H1; i += 256) {
        const float h = hsh[i];
        #pragma unroll
        for (int k = 0; k < 10; ++k) acc[k] = fmaf(h, W2[i * 10 + k], acc[k]);
    }
    for (int k = 0; k < 10; ++k) {
        red[t] = acc[k]; __syncthreads();
        for (int s2 = 128; s2 > 0; s2 >>= 1) {
            if (t < s2) red[t] += red[t + s2];
            __syncthreads();
        }
        if (t == 0) out[k] = red[0] + b2[k];
        __syncthreads();
    }
}

// ---------------- launch ----------------
extern "C" void kernel_launch(void* const* d_in, const int* in_sizes, int n_in,
                              void* d_out, int out_size, void* d_ws, size_t ws_size,
                              hipStream_t stream)
{
    const float* x     = (const float*)d_in[0];
    const float* Wg    = (const float*)d_in[1];
    const float* att_s = (const float*)d_in[2];
    const float* att_d = (const float*)d_in[3];
    const float* b_gat = (const float*)d_in[4];
    const float* Wgcn  = (const float*)d_in[5];
    const float* b_gcn = (const float*)d_in[6];
    const float* W1    = (const float*)d_in[7];
    const float* b1    = (const float*)d_in[8];
    const float* W2    = (const float*)d_in[9];
    const float* b2    = (const float*)d_in[10];
    const int*   ei    = (const int*)d_in[11];
    const int E = in_sizes[11] / 2;
    float* out = (float*)d_out;

    char* wsp = (char*)d_ws;
    size_t off = 0;
    auto alc = [&](size_t b) { void* p = wsp + off; off += (b + 255) & ~(size_t)255; return p; };
    float* bufA   = (float*)alc((size_t)NN * HDIM * 4);   // xl, later xw
    float* bufB   = (float*)alc((size_t)NN * HDIM * 4);   // x1, later x2
    float* aS     = (float*)alc((size_t)NN * HH * 4);
    float* aD     = (float*)alc((size_t)NN * HH * 4);
    float* mB     = (float*)alc((size_t)NN * HH * 4);
    float* dB     = (float*)alc((size_t)NN * HH * 4);
    int*   rowptr = (int*)alc((size_t)(NN + 1) * 4);
    int*   cnt    = (int*)alc((size_t)NN * 4);
    int*   cursor = (int*)alc((size_t)NN * 4);
    int*   csr    = (int*)alc((size_t)(E + NN) * 4);
    float* dinv   = (float*)alc((size_t)NN * 4);
    float* pmax   = (float*)alc((size_t)HDIM * 4);
    float* psum   = (float*)alc((size_t)HDIM * 4);
    float* hacc   = (float*)alc((size_t)H1 * 4);

    hipMemsetAsync(cnt,    0, (size_t)NN * 4,   stream);
    hipMemsetAsync(cursor, 0, (size_t)NN * 4,   stream);
    hipMemsetAsync(pmax,   0, (size_t)HDIM * 4, stream);
    hipMemsetAsync(psum,   0, (size_t)HDIM * 4, stream);
    hipMemsetAsync(hacc,   0, (size_t)H1 * 4,   stream);

    const int EP = E + NN;
    k_count<<<(EP + 255) / 256, 256, 0, stream>>>(ei, E, cnt);
    k_scan<<<1, 1024, 0, stream>>>(cnt, rowptr, dinv);
    k_fill<<<(EP + 255) / 256, 256, 0, stream>>>(ei, E, rowptr, cursor, csr);
    dim3 g1((NN + 127) / 128, HH);
    k_gemm1<<<g1, 256, 0, stream>>>(x, Wg, att_s, att_d, bufA, aS, aD);
    k_stat<<<(NN * HH + 255) / 256, 256, 0, stream>>>(rowptr, csr, aS, aD, mB, dB);
    k_gat_gather<<<NN, 320, 0, stream>>>(rowptr, csr, aS, aD, mB, dB, bufA, b_gat, bufB);
    dim3 g2((NN + 127) / 128, HDIM / 64);
    k_gemm2<<<g2, 256, 0, stream>>>(bufB, Wgcn, bufA);
    k_gcn_gather<<<NN, 320, 0, stream>>>(rowptr, csr, dinv, bufA, b_gcn, bufB);
    dim3 gp(HDIM / 64, 80);
    k_pool<<<gp, 64, 0, stream>>>(bufB, pmax, psum);
    dim3 gm1(6, 16);
    k_mlp1<<<gm1, 256, 0, stream>>>(pmax, psum, W1, hacc);
    k_mlp2<<<1, 256, 0, stream>>>(hacc, b1, W2, b2, out);
}

// Round 3
// 556.332 us; speedup vs baseline: 1.7794x; 1.3396x over previous
//
#include <hip/hip_runtime.h>
#include <hip/hip_bf16.h>
#include <math.h>

#define NN 20000
#define DD 64
#define HH 10
#define HDIM 640
#define NEG 0.2f
#define H1 1500

typedef _Float16 half8 __attribute__((ext_vector_type(8)));
typedef _Float16 half4v __attribute__((ext_vector_type(4)));
typedef _Float16 half2v __attribute__((ext_vector_type(2)));
typedef float f32x4 __attribute__((ext_vector_type(4)));

// ---------------- GEMM1: xl(fp16) = x @ W_gat, fused a_src/a_dst via shuffle ----------------
__global__ __launch_bounds__(256) void k_gemm1(
    const float* __restrict__ x, const float* __restrict__ Wg,
    const float* __restrict__ att_s, const float* __restrict__ att_d,
    _Float16* __restrict__ xl, float* __restrict__ a_src, float* __restrict__ a_dst)
{
    __shared__ float xsT[64][132];   // [k][m], padded
    __shared__ float wsb[64][64];    // [k][n]
    const int tid = threadIdx.x;
    const int m0 = blockIdx.x * 128;
    const int h  = blockIdx.y;
    const int n0 = h * 64;

    #pragma unroll
    for (int j = 0; j < 8; ++j) {
        const int lin = tid + j * 256;
        const int mm = lin >> 4, k4 = (lin & 15) * 4;
        float4 v = {0.f, 0.f, 0.f, 0.f};
        const int row = m0 + mm;
        if (row < NN) v = *(const float4*)&x[(size_t)row * DD + k4];
        xsT[k4 + 0][mm] = v.x; xsT[k4 + 1][mm] = v.y;
        xsT[k4 + 2][mm] = v.z; xsT[k4 + 3][mm] = v.w;
    }
    #pragma unroll
    for (int j = 0; j < 4; ++j) {
        const int lin = tid + j * 256;
        const int kk = lin >> 4, n4 = (lin & 15) * 4;
        *(float4*)&wsb[kk][n4] = *(const float4*)&Wg[(size_t)kk * HDIM + n0 + n4];
    }
    __syncthreads();

    const int cid = tid & 15, rid = tid >> 4;
    const int r0 = rid * 8, cg = cid * 4;
    float acc[8][4];
    #pragma unroll
    for (int i = 0; i < 8; ++i)
        #pragma unroll
        for (int j = 0; j < 4; ++j) acc[i][j] = 0.f;

    #pragma unroll 16
    for (int k = 0; k < 64; ++k) {
        const float4 a0 = *(const float4*)&xsT[k][r0];
        const float4 a1 = *(const float4*)&xsT[k][r0 + 4];
        const float4 b  = *(const float4*)&wsb[k][cg];
        const float av[8] = {a0.x, a0.y, a0.z, a0.w, a1.x, a1.y, a1.z, a1.w};
        const float bv[4] = {b.x, b.y, b.z, b.w};
        #pragma unroll
        for (int i = 0; i < 8; ++i)
            #pragma unroll
            for (int j = 0; j < 4; ++j)
                acc[i][j] = fmaf(av[i], bv[j], acc[i][j]);
    }

    const float4 as4 = *(const float4*)&att_s[h * DD + cg];
    const float4 ad4 = *(const float4*)&att_d[h * DD + cg];
    #pragma unroll
    for (int i = 0; i < 8; ++i) {
        const int row = m0 + r0 + i;
        float ps = acc[i][0] * as4.x + acc[i][1] * as4.y + acc[i][2] * as4.z + acc[i][3] * as4.w;
        float pd = acc[i][0] * ad4.x + acc[i][1] * ad4.y + acc[i][2] * ad4.z + acc[i][3] * ad4.w;
        #pragma unroll
        for (int off = 8; off > 0; off >>= 1) {
            ps += __shfl_down(ps, off, 16);
            pd += __shfl_down(pd, off, 16);
        }
        if (row < NN) {
            half4v o = {(_Float16)acc[i][0], (_Float16)acc[i][1],
                        (_Float16)acc[i][2], (_Float16)acc[i][3]};
            *(half4v*)&xl[(size_t)row * HDIM + n0 + cg] = o;
            if (cid == 0) {
                a_src[row * HH + h] = ps;
                a_dst[row * HH + h] = pd;
            }
        }
    }
}

// ---------------- CSR build ----------------
__global__ void k_count(const int* __restrict__ ei, int E, int* __restrict__ cnt)
{
    const int e = blockIdx.x * blockDim.x + threadIdx.x;
    if (e >= E + NN) return;
    const int d = (e < E) ? ei[E + e] : (e - E);
    atomicAdd(&cnt[d], 1);
}

__global__ __launch_bounds__(1024) void k_scan(const int* __restrict__ cnt,
                                               int* __restrict__ rowptr,
                                               float* __restrict__ dinv)
{
    __shared__ int sh[1024];
    const int t = threadIdx.x;
    const int CH = 20;
    const int base = t * CH;
    int loc[CH];
    int s = 0;
    #pragma unroll
    for (int i = 0; i < CH; ++i) {
        const int idx = base + i;
        const int c = (idx < NN) ? cnt[idx] : 0;
        loc[i] = s; s += c;
    }
    sh[t] = s; __syncthreads();
    for (int off = 1; off < 1024; off <<= 1) {
        const int v = (t >= off) ? sh[t - off] : 0;
        __syncthreads();
        sh[t] += v;
        __syncthreads();
    }
    const int prev = (t == 0) ? 0 : sh[t - 1];
    #pragma unroll
    for (int i = 0; i < CH; ++i) {
        const int idx = base + i;
        if (idx < NN) {
            rowptr[idx] = prev + loc[i];
            dinv[idx]   = rsqrtf((float)cnt[idx]);
        }
    }
    if (t == 1023) rowptr[NN] = sh[1023];
}

__global__ void k_fill(const int* __restrict__ ei, int E,
                       const int* __restrict__ rowptr,
                       int* __restrict__ cursor, int* __restrict__ csr)
{
    const int e = blockIdx.x * blockDim.x + threadIdx.x;
    if (e >= E + NN) return;
    int s, d;
    if (e < E) { s = ei[e]; d = ei[E + e]; } else { s = d = e - E; }
    const int pos = atomicAdd(&cursor[d], 1);
    csr[rowptr[d] + pos] = s;
}

// ---------------- per-(node,head) online softmax stats ----------------
__global__ void k_stat(const int* __restrict__ rowptr, const int* __restrict__ csr,
                       const float* __restrict__ a_src, const float* __restrict__ a_dst,
                       float* __restrict__ mbuf, float* __restrict__ dbuf)
{
    const int g = blockIdx.x * blockDim.x + threadIdx.x;
    if (g >= NN * HH) return;
    const int n = g / HH, h = g - n * HH;
    const float adn = a_dst[g];
    const int j0 = rowptr[n], j1 = rowptr[n + 1];
    float mx = -INFINITY, dn = 0.f;
    for (int j = j0; j < j1; ++j) {
        const int s = csr[j];
        float av = a_src[s * HH + h] + adn;
        av = (av >= 0.f) ? av : NEG * av;
        if (av > mx) { dn = dn * __expf(mx - av) + 1.f; mx = av; }
        else         { dn += __expf(av - mx); }
    }
    mbuf[g] = mx; dbuf[g] = dn;
}

// ---------------- GAT gather: x1(fp16) = relu(segsum(w*xl[src]) + b_gat) ----------------
__global__ __launch_bounds__(320) void k_gat_gather(
    const int* __restrict__ rowptr, const int* __restrict__ csr,
    const float* __restrict__ a_src, const float* __restrict__ a_dst,
    const float* __restrict__ mbuf, const float* __restrict__ dbuf,
    const _Float16* __restrict__ xl, const float* __restrict__ b_gat,
    _Float16* __restrict__ x1)
{
    const int n = blockIdx.x, tid = threadIdx.x;
    const int c0 = tid * 2;
    const int h = tid >> 5;                 // 2 adjacent cols share a head
    const float ad = a_dst[n * HH + h];
    const float m  = mbuf[n * HH + h];
    const float rr = 1.f / (dbuf[n * HH + h] + 1e-16f);
    float acc0 = 0.f, acc1 = 0.f;
    const int j0 = rowptr[n], j1 = rowptr[n + 1];
    for (int j = j0; j < j1; ++j) {
        const int s = csr[j];
        float av = a_src[s * HH + h] + ad;
        av = (av >= 0.f) ? av : NEG * av;
        const float w = __expf(av - m) * rr;
        const half2v xv = *(const half2v*)&xl[(size_t)s * HDIM + c0];
        acc0 = fmaf(w, (float)xv.x, acc0);
        acc1 = fmaf(w, (float)xv.y, acc1);
    }
    float v0 = acc0 + b_gat[c0];
    float v1 = acc1 + b_gat[c0 + 1];
    half2v o = {(_Float16)((v0 > 0.f) ? v0 : 0.f), (_Float16)((v1 > 0.f) ? v1 : 0.f)};
    *(half2v*)&x1[(size_t)n * HDIM + c0] = o;
}

// ---------------- W_gcn transpose + fp16 convert: Wbt[n][k] = W[k][n] ----------------
__global__ __launch_bounds__(256) void k_cvtW(const float* __restrict__ W,
                                              _Float16* __restrict__ Wbt)
{
    __shared__ float t[32][33];
    const int bx = blockIdx.x, by = blockIdx.y;   // bx: n-tile, by: k-tile
    const int lx = threadIdx.x & 31, ly = threadIdx.x >> 5;
    #pragma unroll
    for (int i = ly; i < 32; i += 8)
        t[i][lx] = W[(size_t)(by * 32 + i) * HDIM + bx * 32 + lx];
    __syncthreads();
    #pragma unroll
    for (int j = ly; j < 32; j += 8)
        Wbt[(size_t)(bx * 32 + j) * HDIM + by * 32 + lx] = (_Float16)t[lx][j];
}

// ---------------- GEMM2: xw(fp16) = x1 @ W_gcn via MFMA fp16 ----------------
__global__ __launch_bounds__(256) void k_gemm2(const _Float16* __restrict__ X,
                                               const _Float16* __restrict__ Wbt,
                                               _Float16* __restrict__ Y)
{
    __shared__ _Float16 As[128][40];   // [m][k], k-stride 80 B
    __shared__ _Float16 Bs[128][40];   // [n][k]
    const int tid = threadIdx.x;
    const int m0 = blockIdx.x * 128, n0 = blockIdx.y * 128;
    const int lane = tid & 63, wave = tid >> 6;
    const int l15 = lane & 15, quad = lane >> 4;

    f32x4 acc[2][8];
    #pragma unroll
    for (int r = 0; r < 2; ++r)
        #pragma unroll
        for (int c = 0; c < 8; ++c) acc[r][c] = (f32x4){0.f, 0.f, 0.f, 0.f};

    for (int kb = 0; kb < HDIM; kb += 32) {
        #pragma unroll
        for (int j = 0; j < 2; ++j) {
            const int cc = tid + j * 256;
            const int row = cc >> 2, part = cc & 3;
            const int gr = m0 + row;
            half8 v = {0, 0, 0, 0, 0, 0, 0, 0};
            if (gr < NN) v = *(const half8*)&X[(size_t)gr * HDIM + kb + part * 8];
            *(half8*)&As[row][part * 8] = v;
        }
        #pragma unroll
        for (int j = 0; j < 2; ++j) {
            const int cc = tid + j * 256;
            const int row = cc >> 2, part = cc & 3;
            *(half8*)&Bs[row][part * 8] =
                *(const half8*)&Wbt[(size_t)(n0 + row) * HDIM + kb + part * 8];
        }
        __syncthreads();
        const half8 a0 = *(const half8*)&As[wave * 32 + l15][quad * 8];
        const half8 a1 = *(const half8*)&As[wave * 32 + 16 + l15][quad * 8];
        #pragma unroll
        for (int c = 0; c < 8; ++c) {
            const half8 b = *(const half8*)&Bs[c * 16 + l15][quad * 8];
            acc[0][c] = __builtin_amdgcn_mfma_f32_16x16x32_f16(a0, b, acc[0][c], 0, 0, 0);
            acc[1][c] = __builtin_amdgcn_mfma_f32_16x16x32_f16(a1, b, acc[1][c], 0, 0, 0);
        }
        __syncthreads();
    }
    #pragma unroll
    for (int r = 0; r < 2; ++r) {
        #pragma unroll
        for (int c = 0; c < 8; ++c) {
            #pragma unroll
            for (int g = 0; g < 4; ++g) {
                const int row = m0 + wave * 32 + r * 16 + quad * 4 + g;
                if (row < NN)
                    Y[(size_t)row * HDIM + n0 + c * 16 + l15] = (_Float16)acc[r][c][g];
            }
        }
    }
}

// ---------------- GCN gather: x2(fp32) = relu(segsum(norm*xw[src]) + b_gcn) ----------------
__global__ __launch_bounds__(320) void k_gcn_gather(
    const int* __restrict__ rowptr, const int* __restrict__ csr,
    const float* __restrict__ dinv, const _Float16* __restrict__ xw,
    const float* __restrict__ b_gcn, float* __restrict__ x2)
{
    const int n = blockIdx.x, tid = threadIdx.x;
    const int c0 = tid * 2;
    const float dn = dinv[n];
    float acc0 = 0.f, acc1 = 0.f;
    const int j0 = rowptr[n], j1 = rowptr[n + 1];
    for (int j = j0; j < j1; ++j) {
        const int s = csr[j];
        const float wt = dinv[s] * dn;
        const half2v xv = *(const half2v*)&xw[(size_t)s * HDIM + c0];
        acc0 = fmaf(wt, (float)xv.x, acc0);
        acc1 = fmaf(wt, (float)xv.y, acc1);
    }
    float v0 = acc0 + b_gcn[c0];
    float v1 = acc1 + b_gcn[c0 + 1];
    float2 o = {(v0 > 0.f) ? v0 : 0.f, (v1 > 0.f) ? v1 : 0.f};
    *(float2*)&x2[(size_t)n * HDIM + c0] = o;
}

// ---------------- pooling ----------------
__global__ __launch_bounds__(64) void k_pool(const float* __restrict__ x2,
                                             float* __restrict__ pmax,
                                             float* __restrict__ psum)
{
    const int col = blockIdx.x * 64 + threadIdx.x;
    const int nb = blockIdx.y;
    float mx = 0.f, sm = 0.f;
    const int nend = nb * 250 + 250;
    for (int n = nb * 250; n < nend; ++n) {
        const float v = x2[(size_t)n * HDIM + col];
        mx = fmaxf(mx, v); sm += v;
    }
    atomicMax((int*)&pmax[col], __float_as_int(mx));
    atomicAdd(&psum[col], sm);
}

// ---------------- MLP layer 1 (split-K into hacc) ----------------
__global__ __launch_bounds__(256) void k_mlp1(const float* __restrict__ pmax,
                                              const float* __restrict__ psum,
                                              const float* __restrict__ W1,
                                              float* __restrict__ hacc)
{
    __shared__ float pl[80];
    const int t = threadIdx.x;
    const int i0 = blockIdx.y * 80;
    if (t < 80) {
        const int i = i0 + t;
        pl[t] = (i < HDIM) ? pmax[i] : psum[i - HDIM] * (1.0f / NN);
    }
    __syncthreads();
    const int j = blockIdx.x * 256 + t;
    if (j >= H1) return;
    float acc = 0.f;
    #pragma unroll 8
    for (int i = 0; i < 80; ++i)
        acc = fmaf(pl[i], W1[(size_t)(i0 + i) * H1 + j], acc);
    atomicAdd(&hacc[j], acc);
}

// ---------------- MLP layer 2 ----------------
__global__ __launch_bounds__(256) void k_mlp2(const float* __restrict__ hacc,
                                              const float* __restrict__ b1,
                                              const float* __restrict__ W2,
                                              const float* __restrict__ b2,
                                              float* __restrict__ out)
{
    __shared__ float hsh[H1];
    __shared__ float red[256];
    const int t = threadIdx.x;
    for (int i = t; i < H1; i += 256) {
        const float v = hacc[i] + b1[i];
        hsh[i] = (v > 0.f) ? v : 0.f;
    }
    __syncthreads();
    float acc[10];
    #pragma unroll
    for (int k = 0; k < 10; ++k) acc[k] = 0.f;
    for (int i = t; i < H1; i += 256) {
        const float h = hsh[i];
        #pragma unroll
        for (int k = 0; k < 10; ++k) acc[k] = fmaf(h, W2[i * 10 + k], acc[k]);
    }
    for (int k = 0; k < 10; ++k) {
        red[t] = acc[k]; __syncthreads();
        for (int s2 = 128; s2 > 0; s2 >>= 1) {
            if (t < s2) red[t] += red[t + s2];
            __syncthreads();
        }
        if (t == 0) out[k] = red[0] + b2[k];
        __syncthreads();
    }
}

// ---------------- launch ----------------
extern "C" void kernel_launch(void* const* d_in, const int* in_sizes, int n_in,
                              void* d_out, int out_size, void* d_ws, size_t ws_size,
                              hipStream_t stream)
{
    const float* x     = (const float*)d_in[0];
    const float* Wg    = (const float*)d_in[1];
    const float* att_s = (const float*)d_in[2];
    const float* att_d = (const float*)d_in[3];
    const float* b_gat = (const float*)d_in[4];
    const float* Wgcn  = (const float*)d_in[5];
    const float* b_gcn = (const float*)d_in[6];
    const float* W1    = (const float*)d_in[7];
    const float* b1    = (const float*)d_in[8];
    const float* W2    = (const float*)d_in[9];
    const float* b2    = (const float*)d_in[10];
    const int*   ei    = (const int*)d_in[11];
    const int E = in_sizes[11] / 2;
    float* out = (float*)d_out;

    char* wsp = (char*)d_ws;
    size_t off = 0;
    auto alc = [&](size_t b) { void* p = wsp + off; off += (b + 255) & ~(size_t)255; return p; };
    char*  bufA   = (char*)alc((size_t)NN * HDIM * 4);    // xl(fp16), later xw(fp16)
    char*  bufB   = (char*)alc((size_t)NN * HDIM * 4);    // x1(fp16), later x2(fp32)
    float* aS     = (float*)alc((size_t)NN * HH * 4);
    float* aD     = (float*)alc((size_t)NN * HH * 4);
    float* mB     = (float*)alc((size_t)NN * HH * 4);
    float* dB     = (float*)alc((size_t)NN * HH * 4);
    int*   rowptr = (int*)alc((size_t)(NN + 1) * 4);
    int*   cnt    = (int*)alc((size_t)NN * 4);
    int*   cursor = (int*)alc((size_t)NN * 4);
    int*   csr    = (int*)alc((size_t)(E + NN) * 4);
    float* dinv   = (float*)alc((size_t)NN * 4);
    _Float16* Wbt = (_Float16*)alc((size_t)HDIM * HDIM * 2);
    float* pmax   = (float*)alc((size_t)HDIM * 4);
    float* psum   = (float*)alc((size_t)HDIM * 4);
    float* hacc   = (float*)alc((size_t)H1 * 4);

    hipMemsetAsync(cnt,    0, (size_t)NN * 4,   stream);
    hipMemsetAsync(cursor, 0, (size_t)NN * 4,   stream);
    hipMemsetAsync(pmax,   0, (size_t)HDIM * 4, stream);
    hipMemsetAsync(psum,   0, (size_t)HDIM * 4, stream);
    hipMemsetAsync(hacc,   0, (size_t)H1 * 4,   stream);

    const int EP = E + NN;
    k_count<<<(EP + 255) / 256, 256, 0, stream>>>(ei, E, cnt);
    k_scan<<<1, 1024, 0, stream>>>(cnt, rowptr, dinv);
    k_fill<<<(EP + 255) / 256, 256, 0, stream>>>(ei, E, rowptr, cursor, csr);
    dim3 gw(HDIM / 32, HDIM / 32);
    k_cvtW<<<gw, 256, 0, stream>>>(Wgcn, Wbt);
    dim3 g1((NN + 127) / 128, HH);
    k_gemm1<<<g1, 256, 0, stream>>>(x, Wg, att_s, att_d, (_Float16*)bufA, aS, aD);
    k_stat<<<(NN * HH + 255) / 256, 256, 0, stream>>>(rowptr, csr, aS, aD, mB, dB);
    k_gat_gather<<<NN, 320, 0, stream>>>(rowptr, csr, aS, aD, mB, dB,
                                         (const _Float16*)bufA, b_gat, (_Float16*)bufB);
    dim3 g2((NN + 127) / 128, HDIM / 128);
    k_gemm2<<<g2, 256, 0, stream>>>((const _Float16*)bufB, Wbt, (_Float16*)bufA);
    k_gcn_gather<<<NN, 320, 0, stream>>>(rowptr, csr, dinv,
                                         (const _Float16*)bufA, b_gcn, (float*)bufB);
    dim3 gp(HDIM / 64, 80);
    k_pool<<<gp, 64, 0, stream>>>((const float*)bufB, pmax, psum);
    dim3 gm1(6, 16);
    k_mlp1<<<gm1, 256, 0, stream>>>(pmax, psum, W1, hacc);
    k_mlp2<<<1, 256, 0, stream>>>(hacc, b1, W2, b2, out);
}

// Round 4
// 509.684 us; speedup vs baseline: 1.9423x; 1.0915x over previous
//
#include <hip/hip_runtime.h>
#include <hip/hip_bf16.h>
#include <math.h>

#define NN 20000
#define DD 64
#define HH 10
#define HDIM 640
#define NEG 0.2f
#define H1 1500

typedef _Float16 half8 __attribute__((ext_vector_type(8)));
typedef _Float16 half4v __attribute__((ext_vector_type(4)));
typedef _Float16 half2v __attribute__((ext_vector_type(2)));
typedef float f32x4 __attribute__((ext_vector_type(4)));

// ---------------- GEMM1: xl(fp16) = x @ W_gat, fused a_src/a_dst via shuffle ----------------
__global__ __launch_bounds__(256) void k_gemm1(
    const float* __restrict__ x, const float* __restrict__ Wg,
    const float* __restrict__ att_s, const float* __restrict__ att_d,
    _Float16* __restrict__ xl, float* __restrict__ a_src, float* __restrict__ a_dst)
{
    __shared__ float xsT[64][132];   // [k][m], padded
    __shared__ float wsb[64][64];    // [k][n]
    const int tid = threadIdx.x;
    const int m0 = blockIdx.x * 128;
    const int h  = blockIdx.y;
    const int n0 = h * 64;

    #pragma unroll
    for (int j = 0; j < 8; ++j) {
        const int lin = tid + j * 256;
        const int mm = lin >> 4, k4 = (lin & 15) * 4;
        float4 v = {0.f, 0.f, 0.f, 0.f};
        const int row = m0 + mm;
        if (row < NN) v = *(const float4*)&x[(size_t)row * DD + k4];
        xsT[k4 + 0][mm] = v.x; xsT[k4 + 1][mm] = v.y;
        xsT[k4 + 2][mm] = v.z; xsT[k4 + 3][mm] = v.w;
    }
    #pragma unroll
    for (int j = 0; j < 4; ++j) {
        const int lin = tid + j * 256;
        const int kk = lin >> 4, n4 = (lin & 15) * 4;
        *(float4*)&wsb[kk][n4] = *(const float4*)&Wg[(size_t)kk * HDIM + n0 + n4];
    }
    __syncthreads();

    const int cid = tid & 15, rid = tid >> 4;
    const int r0 = rid * 8, cg = cid * 4;
    float acc[8][4];
    #pragma unroll
    for (int i = 0; i < 8; ++i)
        #pragma unroll
        for (int j = 0; j < 4; ++j) acc[i][j] = 0.f;

    #pragma unroll 16
    for (int k = 0; k < 64; ++k) {
        const float4 a0 = *(const float4*)&xsT[k][r0];
        const float4 a1 = *(const float4*)&xsT[k][r0 + 4];
        const float4 b  = *(const float4*)&wsb[k][cg];
        const float av[8] = {a0.x, a0.y, a0.z, a0.w, a1.x, a1.y, a1.z, a1.w};
        const float bv[4] = {b.x, b.y, b.z, b.w};
        #pragma unroll
        for (int i = 0; i < 8; ++i)
            #pragma unroll
            for (int j = 0; j < 4; ++j)
                acc[i][j] = fmaf(av[i], bv[j], acc[i][j]);
    }

    const float4 as4 = *(const float4*)&att_s[h * DD + cg];
    const float4 ad4 = *(const float4*)&att_d[h * DD + cg];
    #pragma unroll
    for (int i = 0; i < 8; ++i) {
        const int row = m0 + r0 + i;
        float ps = acc[i][0] * as4.x + acc[i][1] * as4.y + acc[i][2] * as4.z + acc[i][3] * as4.w;
        float pd = acc[i][0] * ad4.x + acc[i][1] * ad4.y + acc[i][2] * ad4.z + acc[i][3] * ad4.w;
        #pragma unroll
        for (int off = 8; off > 0; off >>= 1) {
            ps += __shfl_down(ps, off, 16);
            pd += __shfl_down(pd, off, 16);
        }
        if (row < NN) {
            half4v o = {(_Float16)acc[i][0], (_Float16)acc[i][1],
                        (_Float16)acc[i][2], (_Float16)acc[i][3]};
            *(half4v*)&xl[(size_t)row * HDIM + n0 + cg] = o;
            if (cid == 0) {
                a_src[row * HH + h] = ps;
                a_dst[row * HH + h] = pd;
            }
        }
    }
}

// ---------------- CSR build ----------------
__global__ void k_count(const int* __restrict__ ei, int E, int* __restrict__ cnt)
{
    const int e = blockIdx.x * blockDim.x + threadIdx.x;
    if (e >= E + NN) return;
    const int d = (e < E) ? ei[E + e] : (e - E);
    atomicAdd(&cnt[d], 1);
}

__global__ __launch_bounds__(1024) void k_scan(const int* __restrict__ cnt,
                                               int* __restrict__ rowptr,
                                               float* __restrict__ dinv)
{
    __shared__ int sh[1024];
    const int t = threadIdx.x;
    const int CH = 20;
    const int base = t * CH;
    int loc[CH];
    int s = 0;
    #pragma unroll
    for (int i = 0; i < CH; ++i) {
        const int idx = base + i;
        const int c = (idx < NN) ? cnt[idx] : 0;
        loc[i] = s; s += c;
    }
    sh[t] = s; __syncthreads();
    for (int off = 1; off < 1024; off <<= 1) {
        const int v = (t >= off) ? sh[t - off] : 0;
        __syncthreads();
        sh[t] += v;
        __syncthreads();
    }
    const int prev = (t == 0) ? 0 : sh[t - 1];
    #pragma unroll
    for (int i = 0; i < CH; ++i) {
        const int idx = base + i;
        if (idx < NN) {
            rowptr[idx] = prev + loc[i];
            dinv[idx]   = rsqrtf((float)cnt[idx]);
        }
    }
    if (t == 1023) rowptr[NN] = sh[1023];
}

// fill CSR + per-edge GCN symmetric norm
__global__ void k_fill(const int* __restrict__ ei, int E,
                       const int* __restrict__ rowptr,
                       int* __restrict__ cursor, int* __restrict__ csr,
                       const float* __restrict__ dinv, float* __restrict__ wn)
{
    const int e = blockIdx.x * blockDim.x + threadIdx.x;
    if (e >= E + NN) return;
    int s, d;
    if (e < E) { s = ei[e]; d = ei[E + e]; } else { s = d = e - E; }
    const int pos = atomicAdd(&cursor[d], 1);
    const int idx = rowptr[d] + pos;
    csr[idx] = s;
    wn[idx]  = dinv[s] * dinv[d];
}

// ---------------- softmax stats + materialized per-edge GAT weights ----------------
__global__ void k_stat(const int* __restrict__ rowptr, const int* __restrict__ csr,
                       const float* __restrict__ a_src, const float* __restrict__ a_dst,
                       float* __restrict__ wgat, int EP)
{
    const int g = blockIdx.x * blockDim.x + threadIdx.x;
    if (g >= NN * HH) return;
    const int n = g / HH, h = g - n * HH;
    const float adn = a_dst[g];
    const int j0 = rowptr[n], j1 = rowptr[n + 1];
    float mx = -INFINITY, dn = 0.f;
    for (int j = j0; j < j1; ++j) {
        const int s = csr[j];
        float av = a_src[s * HH + h] + adn;
        av = (av >= 0.f) ? av : NEG * av;
        if (av > mx) { dn = dn * __expf(mx - av) + 1.f; mx = av; }
        else         { dn += __expf(av - mx); }
    }
    const float rr = 1.f / (dn + 1e-16f);
    float* wp = wgat + (size_t)h * EP;
    for (int j = j0; j < j1; ++j) {
        const int s = csr[j];
        float av = a_src[s * HH + h] + adn;
        av = (av >= 0.f) ? av : NEG * av;
        wp[j] = __expf(av - mx) * rr;
    }
}

// ---------------- GAT gather: x1(fp16) = relu(segsum(w*xl[src]) + b_gat) ----------------
// 2 nodes per 320-block; thread owns 4 adjacent cols (one head per 16 lanes).
__global__ __launch_bounds__(320) void k_gat_gather(
    const int* __restrict__ rowptr, const int* __restrict__ csr,
    const float* __restrict__ wgat, const _Float16* __restrict__ xl,
    const float* __restrict__ b_gat, _Float16* __restrict__ x1, int EP)
{
    const int tid = threadIdx.x;
    const int sub = (tid >= 160) ? 1 : 0;
    const int t   = tid - sub * 160;
    const int n   = blockIdx.x * 2 + sub;
    const int c0  = t * 4;
    const int h   = t >> 4;
    const float* __restrict__ wp = wgat + (size_t)h * EP;
    float a0 = 0.f, a1 = 0.f, a2 = 0.f, a3 = 0.f;
    const int j0 = rowptr[n], j1 = rowptr[n + 1];
    for (int j = j0; j < j1; ++j) {
        const int s = csr[j];
        const float w = wp[j];
        const half4v xv = *(const half4v*)&xl[(size_t)s * HDIM + c0];
        a0 = fmaf(w, (float)xv.x, a0);
        a1 = fmaf(w, (float)xv.y, a1);
        a2 = fmaf(w, (float)xv.z, a2);
        a3 = fmaf(w, (float)xv.w, a3);
    }
    const float4 b = *(const float4*)&b_gat[c0];
    a0 += b.x; a1 += b.y; a2 += b.z; a3 += b.w;
    half4v o = {(_Float16)((a0 > 0.f) ? a0 : 0.f),
                (_Float16)((a1 > 0.f) ? a1 : 0.f),
                (_Float16)((a2 > 0.f) ? a2 : 0.f),
                (_Float16)((a3 > 0.f) ? a3 : 0.f)};
    *(half4v*)&x1[(size_t)n * HDIM + c0] = o;
}

// ---------------- W_gcn transpose + fp16 convert ----------------
__global__ __launch_bounds__(256) void k_cvtW(const float* __restrict__ W,
                                              _Float16* __restrict__ Wbt)
{
    __shared__ float t[32][33];
    const int bx = blockIdx.x, by = blockIdx.y;
    const int lx = threadIdx.x & 31, ly = threadIdx.x >> 5;
    #pragma unroll
    for (int i = ly; i < 32; i += 8)
        t[i][lx] = W[(size_t)(by * 32 + i) * HDIM + bx * 32 + lx];
    __syncthreads();
    #pragma unroll
    for (int j = ly; j < 32; j += 8)
        Wbt[(size_t)(bx * 32 + j) * HDIM + by * 32 + lx] = (_Float16)t[lx][j];
}

// ---------------- GEMM2: xw(fp16) = x1 @ W_gcn via MFMA fp16 ----------------
__global__ __launch_bounds__(256) void k_gemm2(const _Float16* __restrict__ X,
                                               const _Float16* __restrict__ Wbt,
                                               _Float16* __restrict__ Y)
{
    __shared__ _Float16 As[128][40];
    __shared__ _Float16 Bs[128][40];
    const int tid = threadIdx.x;
    const int m0 = blockIdx.x * 128, n0 = blockIdx.y * 128;
    const int lane = tid & 63, wave = tid >> 6;
    const int l15 = lane & 15, quad = lane >> 4;

    f32x4 acc[2][8];
    #pragma unroll
    for (int r = 0; r < 2; ++r)
        #pragma unroll
        for (int c = 0; c < 8; ++c) acc[r][c] = (f32x4){0.f, 0.f, 0.f, 0.f};

    for (int kb = 0; kb < HDIM; kb += 32) {
        #pragma unroll
        for (int j = 0; j < 2; ++j) {
            const int cc = tid + j * 256;
            const int row = cc >> 2, part = cc & 3;
            const int gr = m0 + row;
            half8 v = {0, 0, 0, 0, 0, 0, 0, 0};
            if (gr < NN) v = *(const half8*)&X[(size_t)gr * HDIM + kb + part * 8];
            *(half8*)&As[row][part * 8] = v;
        }
        #pragma unroll
        for (int j = 0; j < 2; ++j) {
            const int cc = tid + j * 256;
            const int row = cc >> 2, part = cc & 3;
            *(half8*)&Bs[row][part * 8] =
                *(const half8*)&Wbt[(size_t)(n0 + row) * HDIM + kb + part * 8];
        }
        __syncthreads();
        const half8 a0 = *(const half8*)&As[wave * 32 + l15][quad * 8];
        const half8 a1 = *(const half8*)&As[wave * 32 + 16 + l15][quad * 8];
        #pragma unroll
        for (int c = 0; c < 8; ++c) {
            const half8 b = *(const half8*)&Bs[c * 16 + l15][quad * 8];
            acc[0][c] = __builtin_amdgcn_mfma_f32_16x16x32_f16(a0, b, acc[0][c], 0, 0, 0);
            acc[1][c] = __builtin_amdgcn_mfma_f32_16x16x32_f16(a1, b, acc[1][c], 0, 0, 0);
        }
        __syncthreads();
    }
    #pragma unroll
    for (int r = 0; r < 2; ++r) {
        #pragma unroll
        for (int c = 0; c < 8; ++c) {
            #pragma unroll
            for (int g = 0; g < 4; ++g) {
                const int row = m0 + wave * 32 + r * 16 + quad * 4 + g;
                if (row < NN)
                    Y[(size_t)row * HDIM + n0 + c * 16 + l15] = (_Float16)acc[r][c][g];
            }
        }
    }
}

// ---------------- GCN gather: x2(fp16) = relu(segsum(wn*xw[src]) + b_gcn) ----------------
// one wave per node; lane owns 10 cols (16B + 4B loads).
__global__ __launch_bounds__(256) void k_gcn_gather(
    const int* __restrict__ rowptr, const int* __restrict__ csr,
    const float* __restrict__ wn, const _Float16* __restrict__ xw,
    const float* __restrict__ b_gcn, _Float16* __restrict__ x2)
{
    const int wave = threadIdx.x >> 6, lane = threadIdx.x & 63;
    const int n = blockIdx.x * 4 + wave;
    const int c0 = lane * 10;
    float acc[10];
    #pragma unroll
    for (int i = 0; i < 10; ++i) acc[i] = 0.f;
    const int j0 = rowptr[n], j1 = rowptr[n + 1];
    for (int j = j0; j < j1; ++j) {
        const int s = csr[j];
        const float w = wn[j];
        const _Float16* xr = &xw[(size_t)s * HDIM + c0];
        const half8  v8 = *(const half8*)xr;
        const half2v v2 = *(const half2v*)(xr + 8);
        #pragma unroll
        for (int i = 0; i < 8; ++i) acc[i] = fmaf(w, (float)v8[i], acc[i]);
        acc[8] = fmaf(w, (float)v2.x, acc[8]);
        acc[9] = fmaf(w, (float)v2.y, acc[9]);
    }
    const float4 b0 = *(const float4*)&b_gcn[c0];
    const float4 b1 = *(const float4*)&b_gcn[c0 + 4];
    const float2 b2 = *(const float2*)&b_gcn[c0 + 8];
    const float bb[10] = {b0.x, b0.y, b0.z, b0.w, b1.x, b1.y, b1.z, b1.w, b2.x, b2.y};
    half8 o8; half2v o2;
    #pragma unroll
    for (int i = 0; i < 8; ++i) {
        const float v = acc[i] + bb[i];
        o8[i] = (_Float16)((v > 0.f) ? v : 0.f);
    }
    {
        const float v8v = acc[8] + bb[8], v9 = acc[9] + bb[9];
        o2.x = (_Float16)((v8v > 0.f) ? v8v : 0.f);
        o2.y = (_Float16)((v9 > 0.f) ? v9 : 0.f);
    }
    _Float16* yr = &x2[(size_t)n * HDIM + c0];
    *(half8*)yr = o8;
    *(half2v*)(yr + 8) = o2;
}

// ---------------- pooling (x2 fp16) ----------------
__global__ __launch_bounds__(64) void k_pool(const _Float16* __restrict__ x2,
                                             float* __restrict__ pmax,
                                             float* __restrict__ psum)
{
    const int t = threadIdx.x;
    const int col = blockIdx.x * 128 + t * 2;
    const int nb = blockIdx.y;
    float mx0 = 0.f, mx1 = 0.f, s0 = 0.f, s1 = 0.f;
    const int nend = nb * 250 + 250;
    for (int n = nb * 250; n < nend; ++n) {
        const half2v v = *(const half2v*)&x2[(size_t)n * HDIM + col];
        const float v0 = (float)v.x, v1 = (float)v.y;
        mx0 = fmaxf(mx0, v0); mx1 = fmaxf(mx1, v1);
        s0 += v0; s1 += v1;
    }
    atomicMax((int*)&pmax[col],     __float_as_int(mx0));
    atomicMax((int*)&pmax[col + 1], __float_as_int(mx1));
    atomicAdd(&psum[col],     s0);
    atomicAdd(&psum[col + 1], s1);
}

// ---------------- MLP layer 1 (split-K into hacc) ----------------
__global__ __launch_bounds__(256) void k_mlp1(const float* __restrict__ pmax,
                                              const float* __restrict__ psum,
                                              const float* __restrict__ W1,
                                              float* __restrict__ hacc)
{
    __shared__ float pl[80];
    const int t = threadIdx.x;
    const int i0 = blockIdx.y * 80;
    if (t < 80) {
        const int i = i0 + t;
        pl[t] = (i < HDIM) ? pmax[i] : psum[i - HDIM] * (1.0f / NN);
    }
    __syncthreads();
    const int j = blockIdx.x * 256 + t;
    if (j >= H1) return;
    float acc = 0.f;
    #pragma unroll 8
    for (int i = 0; i < 80; ++i)
        acc = fmaf(pl[i], W1[(size_t)(i0 + i) * H1 + j], acc);
    atomicAdd(&hacc[j], acc);
}

// ---------------- MLP layer 2 ----------------
__global__ __launch_bounds__(256) void k_mlp2(const float* __restrict__ hacc,
                                              const float* __restrict__ b1,
                                              const float* __restrict__ W2,
                                              const float* __restrict__ b2,
                                              float* __restrict__ out)
{
    __shared__ float hsh[H1];
    __shared__ float red[256];
    const int t = threadIdx.x;
    for (int i = t; i < H1; i += 256) {
        const float v = hacc[i] + b1[i];
        hsh[i] = (v > 0.f) ? v : 0.f;
    }
    __syncthreads();
    float acc[10];
    #pragma unroll
    for (int k = 0; k < 10; ++k) acc[k] = 0.f;
    for (int i = t; i < H1; i += 256) {
        const float h = hsh[i];
        #pragma unroll
        for (int k = 0; k < 10; ++k) acc[k] = fmaf(h, W2[i * 10 + k], acc[k]);
    }
    for (int k = 0; k < 10; ++k) {
        red[t] = acc[k]; __syncthreads();
        for (int s2 = 128; s2 > 0; s2 >>= 1) {
            if (t < s2) red[t] += red[t + s2];
            __syncthreads();
        }
        if (t == 0) out[k] = red[0] + b2[k];
        __syncthreads();
    }
}

// ---------------- launch ----------------
extern "C" void kernel_launch(void* const* d_in, const int* in_sizes, int n_in,
                              void* d_out, int out_size, void* d_ws, size_t ws_size,
                              hipStream_t stream)
{
    const float* x     = (const float*)d_in[0];
    const float* Wg    = (const float*)d_in[1];
    const float* att_s = (const float*)d_in[2];
    const float* att_d = (const float*)d_in[3];
    const float* b_gat = (const float*)d_in[4];
    const float* Wgcn  = (const float*)d_in[5];
    const float* b_gcn = (const float*)d_in[6];
    const float* W1    = (const float*)d_in[7];
    const float* b1    = (const float*)d_in[8];
    const float* W2    = (const float*)d_in[9];
    const float* b2    = (const float*)d_in[10];
    const int*   ei    = (const int*)d_in[11];
    const int E = in_sizes[11] / 2;
    const int EP = E + NN;
    float* out = (float*)d_out;

    char* wsp = (char*)d_ws;
    size_t off = 0;
    auto alc = [&](size_t b) { void* p = wsp + off; off += (b + 255) & ~(size_t)255; return p; };
    _Float16* bufA = (_Float16*)alc((size_t)NN * HDIM * 2);  // xl, later xw
    _Float16* bufB = (_Float16*)alc((size_t)NN * HDIM * 2);  // x1, later x2
    float* aS     = (float*)alc((size_t)NN * HH * 4);
    float* aD     = (float*)alc((size_t)NN * HH * 4);
    int*   rowptr = (int*)alc((size_t)(NN + 1) * 4);
    int*   cnt    = (int*)alc((size_t)NN * 4);
    int*   cursor = (int*)alc((size_t)NN * 4);
    int*   csr    = (int*)alc((size_t)EP * 4);
    float* dinv   = (float*)alc((size_t)NN * 4);
    float* wn     = (float*)alc((size_t)EP * 4);
    float* wgat   = (float*)alc((size_t)HH * EP * 4);
    _Float16* Wbt = (_Float16*)alc((size_t)HDIM * HDIM * 2);
    float* pmax   = (float*)alc((size_t)HDIM * 4);
    float* psum   = (float*)alc((size_t)HDIM * 4);
    float* hacc   = (float*)alc((size_t)H1 * 4);

    hipMemsetAsync(cnt,    0, (size_t)NN * 4,   stream);
    hipMemsetAsync(cursor, 0, (size_t)NN * 4,   stream);
    hipMemsetAsync(pmax,   0, (size_t)HDIM * 4, stream);
    hipMemsetAsync(psum,   0, (size_t)HDIM * 4, stream);
    hipMemsetAsync(hacc,   0, (size_t)H1 * 4,   stream);

    k_count<<<(EP + 255) / 256, 256, 0, stream>>>(ei, E, cnt);
    k_scan<<<1, 1024, 0, stream>>>(cnt, rowptr, dinv);
    k_fill<<<(EP + 255) / 256, 256, 0, stream>>>(ei, E, rowptr, cursor, csr, dinv, wn);
    dim3 gw(HDIM / 32, HDIM / 32);
    k_cvtW<<<gw, 256, 0, stream>>>(Wgcn, Wbt);
    dim3 g1((NN + 127) / 128, HH);
    k_gemm1<<<g1, 256, 0, stream>>>(x, Wg, att_s, att_d, bufA, aS, aD);
    k_stat<<<(NN * HH + 255) / 256, 256, 0, stream>>>(rowptr, csr, aS, aD, wgat, EP);
    k_gat_gather<<<NN / 2, 320, 0, stream>>>(rowptr, csr, wgat, bufA, b_gat, bufB, EP);
    dim3 g2((NN + 127) / 128, HDIM / 128);
    k_gemm2<<<g2, 256, 0, stream>>>(bufB, Wbt, bufA);
    k_gcn_gather<<<NN / 4, 256, 0, stream>>>(rowptr, csr, wn, bufA, b_gcn, bufB);
    dim3 gp(HDIM / 128, 80);
    k_pool<<<gp, 64, 0, stream>>>(bufB, pmax, psum);
    dim3 gm1(6, 16);
    k_mlp1<<<gm1, 256, 0, stream>>>(pmax, psum, W1, hacc);
    k_mlp2<<<1, 256, 0, stream>>>(hacc, b1, W2, b2, out);
}

// Round 5
// 433.203 us; speedup vs baseline: 2.2852x; 1.1765x over previous
//
#include <hip/hip_runtime.h>
#include <hip/hip_bf16.h>
#include <math.h>

#define NN 20000
#define DD 64
#define HH 10
#define HDIM 640
#define NEG 0.2f
#define H1 1500

typedef _Float16 half8 __attribute__((ext_vector_type(8)));
typedef _Float16 half4v __attribute__((ext_vector_type(4)));
typedef _Float16 half2v __attribute__((ext_vector_type(2)));
typedef float f32x4 __attribute__((ext_vector_type(4)));

// ---------------- GEMM1: xl(fp16) = x @ W_gat, fused a_src/a_dst via shuffle ----------------
__global__ __launch_bounds__(256) void k_gemm1(
    const float* __restrict__ x, const float* __restrict__ Wg,
    const float* __restrict__ att_s, const float* __restrict__ att_d,
    _Float16* __restrict__ xl, float* __restrict__ a_src, float* __restrict__ a_dst)
{
    __shared__ float xsT[64][132];   // [k][m], padded
    __shared__ float wsb[64][64];    // [k][n]
    const int tid = threadIdx.x;
    const int m0 = blockIdx.x * 128;
    const int h  = blockIdx.y;
    const int n0 = h * 64;

    #pragma unroll
    for (int j = 0; j < 8; ++j) {
        const int lin = tid + j * 256;
        const int mm = lin >> 4, k4 = (lin & 15) * 4;
        float4 v = {0.f, 0.f, 0.f, 0.f};
        const int row = m0 + mm;
        if (row < NN) v = *(const float4*)&x[(size_t)row * DD + k4];
        xsT[k4 + 0][mm] = v.x; xsT[k4 + 1][mm] = v.y;
        xsT[k4 + 2][mm] = v.z; xsT[k4 + 3][mm] = v.w;
    }
    #pragma unroll
    for (int j = 0; j < 4; ++j) {
        const int lin = tid + j * 256;
        const int kk = lin >> 4, n4 = (lin & 15) * 4;
        *(float4*)&wsb[kk][n4] = *(const float4*)&Wg[(size_t)kk * HDIM + n0 + n4];
    }
    __syncthreads();

    const int cid = tid & 15, rid = tid >> 4;
    const int r0 = rid * 8, cg = cid * 4;
    float acc[8][4];
    #pragma unroll
    for (int i = 0; i < 8; ++i)
        #pragma unroll
        for (int j = 0; j < 4; ++j) acc[i][j] = 0.f;

    #pragma unroll 16
    for (int k = 0; k < 64; ++k) {
        const float4 a0 = *(const float4*)&xsT[k][r0];
        const float4 a1 = *(const float4*)&xsT[k][r0 + 4];
        const float4 b  = *(const float4*)&wsb[k][cg];
        const float av[8] = {a0.x, a0.y, a0.z, a0.w, a1.x, a1.y, a1.z, a1.w};
        const float bv[4] = {b.x, b.y, b.z, b.w};
        #pragma unroll
        for (int i = 0; i < 8; ++i)
            #pragma unroll
            for (int j = 0; j < 4; ++j)
                acc[i][j] = fmaf(av[i], bv[j], acc[i][j]);
    }

    const float4 as4 = *(const float4*)&att_s[h * DD + cg];
    const float4 ad4 = *(const float4*)&att_d[h * DD + cg];
    #pragma unroll
    for (int i = 0; i < 8; ++i) {
        const int row = m0 + r0 + i;
        float ps = acc[i][0] * as4.x + acc[i][1] * as4.y + acc[i][2] * as4.z + acc[i][3] * as4.w;
        float pd = acc[i][0] * ad4.x + acc[i][1] * ad4.y + acc[i][2] * ad4.z + acc[i][3] * ad4.w;
        #pragma unroll
        for (int off = 8; off > 0; off >>= 1) {
            ps += __shfl_down(ps, off, 16);
            pd += __shfl_down(pd, off, 16);
        }
        if (row < NN) {
            half4v o = {(_Float16)acc[i][0], (_Float16)acc[i][1],
                        (_Float16)acc[i][2], (_Float16)acc[i][3]};
            *(half4v*)&xl[(size_t)row * HDIM + n0 + cg] = o;
            if (cid == 0) {
                a_src[row * HH + h] = ps;
                a_dst[row * HH + h] = pd;
            }
        }
    }
}

// ---------------- CSR build ----------------
__global__ void k_count(const int* __restrict__ ei, int E, int* __restrict__ cnt)
{
    const int e = blockIdx.x * blockDim.x + threadIdx.x;
    if (e >= E + NN) return;
    const int d = (e < E) ? ei[E + e] : (e - E);
    atomicAdd(&cnt[d], 1);
}

__global__ __launch_bounds__(1024) void k_scan(const int* __restrict__ cnt,
                                               int* __restrict__ rowptr,
                                               float* __restrict__ dinv)
{
    __shared__ int sh[1024];
    const int t = threadIdx.x;
    const int CH = 20;
    const int base = t * CH;
    int loc[CH];
    int s = 0;
    #pragma unroll
    for (int i = 0; i < CH; ++i) {
        const int idx = base + i;
        const int c = (idx < NN) ? cnt[idx] : 0;
        loc[i] = s; s += c;
    }
    sh[t] = s; __syncthreads();
    for (int off = 1; off < 1024; off <<= 1) {
        const int v = (t >= off) ? sh[t - off] : 0;
        __syncthreads();
        sh[t] += v;
        __syncthreads();
    }
    const int prev = (t == 0) ? 0 : sh[t - 1];
    #pragma unroll
    for (int i = 0; i < CH; ++i) {
        const int idx = base + i;
        if (idx < NN) {
            rowptr[idx] = prev + loc[i];
            dinv[idx]   = rsqrtf((float)cnt[idx]);
        }
    }
    if (t == 1023) rowptr[NN] = sh[1023];
}

// fill CSR + per-edge GCN symmetric norm
__global__ void k_fill(const int* __restrict__ ei, int E,
                       const int* __restrict__ rowptr,
                       int* __restrict__ cursor, int* __restrict__ csr,
                       const float* __restrict__ dinv, float* __restrict__ wn)
{
    const int e = blockIdx.x * blockDim.x + threadIdx.x;
    if (e >= E + NN) return;
    int s, d;
    if (e < E) { s = ei[e]; d = ei[E + e]; } else { s = d = e - E; }
    const int pos = atomicAdd(&cursor[d], 1);
    const int idx = rowptr[d] + pos;
    csr[idx] = s;
    wn[idx]  = dinv[s] * dinv[d];
}

// ---------------- softmax stats: e = exp(leaky(alpha)) (UNnormalized) + den ----------------
// wgat layout [edge][head] (interleaved) so gather reads hit one cache line per edge.
// No max-subtraction: |alpha| <= ~10 here, exp is fp32-safe; only reorders rounding.
__global__ void k_stat(const int* __restrict__ rowptr, const int* __restrict__ csr,
                       const float* __restrict__ a_src, const float* __restrict__ a_dst,
                       float* __restrict__ wgat, float* __restrict__ den)
{
    const int g = blockIdx.x * blockDim.x + threadIdx.x;
    if (g >= NN * HH) return;
    const int n = g / HH, h = g - n * HH;
    const float adn = a_dst[g];
    const int j0 = rowptr[n], j1 = rowptr[n + 1];
    float dn = 0.f;
    for (int j = j0; j < j1; ++j) {
        const int s = csr[j];
        float av = a_src[s * HH + h] + adn;
        av = (av >= 0.f) ? av : NEG * av;
        const float e = __expf(av);
        wgat[(size_t)j * HH + h] = e;
        dn += e;
    }
    den[g] = dn;
}

// ---------------- GAT gather: one wave per node, aligned 16B lanes ----------------
// lane owns cols [lane*8, lane*8+8); lanes 0..15 also own [512+lane*8, ...).
// Normalization (1/den) applied once at epilogue.
__global__ __launch_bounds__(256) void k_gat_gather(
    const int* __restrict__ rowptr, const int* __restrict__ csr,
    const float* __restrict__ wgat, const float* __restrict__ den,
    const _Float16* __restrict__ xl, const float* __restrict__ b_gat,
    _Float16* __restrict__ x1)
{
    const int wave = threadIdx.x >> 6, lane = threadIdx.x & 63;
    const int n = blockIdx.x * 4 + wave;
    const int c0 = lane * 8;
    const int h0 = lane >> 3;
    const bool dual = (lane < 16);
    const int c1 = 512 + lane * 8;
    const int h1 = 8 + (lane >> 3);

    float acc0[8], acc1[8];
    #pragma unroll
    for (int i = 0; i < 8; ++i) { acc0[i] = 0.f; acc1[i] = 0.f; }

    const int j0 = rowptr[n], j1 = rowptr[n + 1];
    int j = j0;
    for (; j + 1 < j1; j += 2) {
        const int sA = csr[j], sB = csr[j + 1];
        const float wA0 = wgat[(size_t)j * HH + h0];
        const float wB0 = wgat[(size_t)(j + 1) * HH + h0];
        const half8 vA0 = *(const half8*)&xl[(size_t)sA * HDIM + c0];
        const half8 vB0 = *(const half8*)&xl[(size_t)sB * HDIM + c0];
        #pragma unroll
        for (int i = 0; i < 8; ++i) {
            acc0[i] = fmaf(wA0, (float)vA0[i], acc0[i]);
            acc0[i] = fmaf(wB0, (float)vB0[i], acc0[i]);
        }
        if (dual) {
            const float wA1 = wgat[(size_t)j * HH + h1];
            const float wB1 = wgat[(size_t)(j + 1) * HH + h1];
            const half8 vA1 = *(const half8*)&xl[(size_t)sA * HDIM + c1];
            const half8 vB1 = *(const half8*)&xl[(size_t)sB * HDIM + c1];
            #pragma unroll
            for (int i = 0; i < 8; ++i) {
                acc1[i] = fmaf(wA1, (float)vA1[i], acc1[i]);
                acc1[i] = fmaf(wB1, (float)vB1[i], acc1[i]);
            }
        }
    }
    if (j < j1) {
        const int sA = csr[j];
        const float wA0 = wgat[(size_t)j * HH + h0];
        const half8 vA0 = *(const half8*)&xl[(size_t)sA * HDIM + c0];
        #pragma unroll
        for (int i = 0; i < 8; ++i) acc0[i] = fmaf(wA0, (float)vA0[i], acc0[i]);
        if (dual) {
            const float wA1 = wgat[(size_t)j * HH + h1];
            const half8 vA1 = *(const half8*)&xl[(size_t)sA * HDIM + c1];
            #pragma unroll
            for (int i = 0; i < 8; ++i) acc1[i] = fmaf(wA1, (float)vA1[i], acc1[i]);
        }
    }

    {
        const float rr = 1.f / (den[n * HH + h0] + 1e-16f);
        const float4 ba = *(const float4*)&b_gat[c0];
        const float4 bb = *(const float4*)&b_gat[c0 + 4];
        const float bv[8] = {ba.x, ba.y, ba.z, ba.w, bb.x, bb.y, bb.z, bb.w};
        half8 o;
        #pragma unroll
        for (int i = 0; i < 8; ++i) {
            const float v = fmaf(acc0[i], rr, bv[i]);
            o[i] = (_Float16)((v > 0.f) ? v : 0.f);
        }
        *(half8*)&x1[(size_t)n * HDIM + c0] = o;
    }
    if (dual) {
        const float rr = 1.f / (den[n * HH + h1] + 1e-16f);
        const float4 ba = *(const float4*)&b_gat[c1];
        const float4 bb = *(const float4*)&b_gat[c1 + 4];
        const float bv[8] = {ba.x, ba.y, ba.z, ba.w, bb.x, bb.y, bb.z, bb.w};
        half8 o;
        #pragma unroll
        for (int i = 0; i < 8; ++i) {
            const float v = fmaf(acc1[i], rr, bv[i]);
            o[i] = (_Float16)((v > 0.f) ? v : 0.f);
        }
        *(half8*)&x1[(size_t)n * HDIM + c1] = o;
    }
}

// ---------------- W_gcn transpose + fp16 convert ----------------
__global__ __launch_bounds__(256) void k_cvtW(const float* __restrict__ W,
                                              _Float16* __restrict__ Wbt)
{
    __shared__ float t[32][33];
    const int bx = blockIdx.x, by = blockIdx.y;
    const int lx = threadIdx.x & 31, ly = threadIdx.x >> 5;
    #pragma unroll
    for (int i = ly; i < 32; i += 8)
        t[i][lx] = W[(size_t)(by * 32 + i) * HDIM + bx * 32 + lx];
    __syncthreads();
    #pragma unroll
    for (int j = ly; j < 32; j += 8)
        Wbt[(size_t)(bx * 32 + j) * HDIM + by * 32 + lx] = (_Float16)t[lx][j];
}

// ---------------- GEMM2: xw(fp16) = x1 @ W_gcn via MFMA fp16 ----------------
__global__ __launch_bounds__(256) void k_gemm2(const _Float16* __restrict__ X,
                                               const _Float16* __restrict__ Wbt,
                                               _Float16* __restrict__ Y)
{
    __shared__ _Float16 As[128][40];
    __shared__ _Float16 Bs[128][40];
    const int tid = threadIdx.x;
    const int m0 = blockIdx.x * 128, n0 = blockIdx.y * 128;
    const int lane = tid & 63, wave = tid >> 6;
    const int l15 = lane & 15, quad = lane >> 4;

    f32x4 acc[2][8];
    #pragma unroll
    for (int r = 0; r < 2; ++r)
        #pragma unroll
        for (int c = 0; c < 8; ++c) acc[r][c] = (f32x4){0.f, 0.f, 0.f, 0.f};

    for (int kb = 0; kb < HDIM; kb += 32) {
        #pragma unroll
        for (int j = 0; j < 2; ++j) {
            const int cc = tid + j * 256;
            const int row = cc >> 2, part = cc & 3;
            const int gr = m0 + row;
            half8 v = {0, 0, 0, 0, 0, 0, 0, 0};
            if (gr < NN) v = *(const half8*)&X[(size_t)gr * HDIM + kb + part * 8];
            *(half8*)&As[row][part * 8] = v;
        }
        #pragma unroll
        for (int j = 0; j < 2; ++j) {
            const int cc = tid + j * 256;
            const int row = cc >> 2, part = cc & 3;
            *(half8*)&Bs[row][part * 8] =
                *(const half8*)&Wbt[(size_t)(n0 + row) * HDIM + kb + part * 8];
        }
        __syncthreads();
        const half8 a0 = *(const half8*)&As[wave * 32 + l15][quad * 8];
        const half8 a1 = *(const half8*)&As[wave * 32 + 16 + l15][quad * 8];
        #pragma unroll
        for (int c = 0; c < 8; ++c) {
            const half8 b = *(const half8*)&Bs[c * 16 + l15][quad * 8];
            acc[0][c] = __builtin_amdgcn_mfma_f32_16x16x32_f16(a0, b, acc[0][c], 0, 0, 0);
            acc[1][c] = __builtin_amdgcn_mfma_f32_16x16x32_f16(a1, b, acc[1][c], 0, 0, 0);
        }
        __syncthreads();
    }
    #pragma unroll
    for (int r = 0; r < 2; ++r) {
        #pragma unroll
        for (int c = 0; c < 8; ++c) {
            #pragma unroll
            for (int g = 0; g < 4; ++g) {
                const int row = m0 + wave * 32 + r * 16 + quad * 4 + g;
                if (row < NN)
                    Y[(size_t)row * HDIM + n0 + c * 16 + l15] = (_Float16)acc[r][c][g];
            }
        }
    }
}

// ---------------- GCN gather: one wave per node, aligned 16B lanes ----------------
__global__ __launch_bounds__(256) void k_gcn_gather(
    const int* __restrict__ rowptr, const int* __restrict__ csr,
    const float* __restrict__ wn, const _Float16* __restrict__ xw,
    const float* __restrict__ b_gcn, _Float16* __restrict__ x2)
{
    const int wave = threadIdx.x >> 6, lane = threadIdx.x & 63;
    const int n = blockIdx.x * 4 + wave;
    const int c0 = lane * 8;
    const bool dual = (lane < 16);
    const int c1 = 512 + lane * 8;

    float acc0[8], acc1[8];
    #pragma unroll
    for (int i = 0; i < 8; ++i) { acc0[i] = 0.f; acc1[i] = 0.f; }

    const int j0 = rowptr[n], j1 = rowptr[n + 1];
    int j = j0;
    for (; j + 1 < j1; j += 2) {
        const int sA = csr[j], sB = csr[j + 1];
        const float wA = wn[j], wB = wn[j + 1];
        const half8 vA0 = *(const half8*)&xw[(size_t)sA * HDIM + c0];
        const half8 vB0 = *(const half8*)&xw[(size_t)sB * HDIM + c0];
        #pragma unroll
        for (int i = 0; i < 8; ++i) {
            acc0[i] = fmaf(wA, (float)vA0[i], acc0[i]);
            acc0[i] = fmaf(wB, (float)vB0[i], acc0[i]);
        }
        if (dual) {
            const half8 vA1 = *(const half8*)&xw[(size_t)sA * HDIM + c1];
            const half8 vB1 = *(const half8*)&xw[(size_t)sB * HDIM + c1];
            #pragma unroll
            for (int i = 0; i < 8; ++i) {
                acc1[i] = fmaf(wA, (float)vA1[i], acc1[i]);
                acc1[i] = fmaf(wB, (float)vB1[i], acc1[i]);
            }
        }
    }
    if (j < j1) {
        const int sA = csr[j];
        const float wA = wn[j];
        const half8 vA0 = *(const half8*)&xw[(size_t)sA * HDIM + c0];
        #pragma unroll
        for (int i = 0; i < 8; ++i) acc0[i] = fmaf(wA, (float)vA0[i], acc0[i]);
        if (dual) {
            const half8 vA1 = *(const half8*)&xw[(size_t)sA * HDIM + c1];
            #pragma unroll
            for (int i = 0; i < 8; ++i) acc1[i] = fmaf(wA, (float)vA1[i], acc1[i]);
        }
    }

    {
        const float4 ba = *(const float4*)&b_gcn[c0];
        const float4 bb = *(const float4*)&b_gcn[c0 + 4];
        const float bv[8] = {ba.x, ba.y, ba.z, ba.w, bb.x, bb.y, bb.z, bb.w};
        half8 o;
        #pragma unroll
        for (int i = 0; i < 8; ++i) {
            const float v = acc0[i] + bv[i];
            o[i] = (_Float16)((v > 0.f) ? v : 0.f);
        }
        *(half8*)&x2[(size_t)n * HDIM + c0] = o;
    }
    if (dual) {
        const float4 ba = *(const float4*)&b_gcn[c1];
        const float4 bb = *(const float4*)&b_gcn[c1 + 4];
        const float bv[8] = {ba.x, ba.y, ba.z, ba.w, bb.x, bb.y, bb.z, bb.w};
        half8 o;
        #pragma unroll
        for (int i = 0; i < 8; ++i) {
            const float v = acc1[i] + bv[i];
            o[i] = (_Float16)((v > 0.f) ? v : 0.f);
        }
        *(half8*)&x2[(size_t)n * HDIM + c1] = o;
    }
}

// ---------------- pooling (x2 fp16) ----------------
__global__ __launch_bounds__(64) void k_pool(const _Float16* __restrict__ x2,
                                             float* __restrict__ pmax,
                                             float* __restrict__ psum)
{
    const int t = threadIdx.x;
    const int col = blockIdx.x * 128 + t * 2;
    const int nb = blockIdx.y;
    float mx0 = 0.f, mx1 = 0.f, s0 = 0.f, s1 = 0.f;
    const int nend = nb * 250 + 250;
    for (int n = nb * 250; n < nend; ++n) {
        const half2v v = *(const half2v*)&x2[(size_t)n * HDIM + col];
        const float v0 = (float)v.x, v1 = (float)v.y;
        mx0 = fmaxf(mx0, v0); mx1 = fmaxf(mx1, v1);
        s0 += v0; s1 += v1;
    }
    atomicMax((int*)&pmax[col],     __float_as_int(mx0));
    atomicMax((int*)&pmax[col + 1], __float_as_int(mx1));
    atomicAdd(&psum[col],     s0);
    atomicAdd(&psum[col + 1], s1);
}

// ---------------- MLP layer 1 (split-K into hacc) ----------------
__global__ __launch_bounds__(256) void k_mlp1(const float* __restrict__ pmax,
                                              const float* __restrict__ psum,
                                              const float* __restrict__ W1,
                                              float* __restrict__ hacc)
{
    __shared__ float pl[80];
    const int t = threadIdx.x;
    const int i0 = blockIdx.y * 80;
    if (t < 80) {
        const int i = i0 + t;
        pl[t] = (i < HDIM) ? pmax[i] : psum[i - HDIM] * (1.0f / NN);
    }
    __syncthreads();
    const int j = blockIdx.x * 256 + t;
    if (j >= H1) return;
    float acc = 0.f;
    #pragma unroll 8
    for (int i = 0; i < 80; ++i)
        acc = fmaf(pl[i], W1[(size_t)(i0 + i) * H1 + j], acc);
    atomicAdd(&hacc[j], acc);
}

// ---------------- MLP layer 2 ----------------
__global__ __launch_bounds__(256) void k_mlp2(const float* __restrict__ hacc,
                                              const float* __restrict__ b1,
                                              const float* __restrict__ W2,
                                              const float* __restrict__ b2,
                                              float* __restrict__ out)
{
    __shared__ float hsh[H1];
    __shared__ float red[256];
    const int t = threadIdx.x;
    for (int i = t; i < H1; i += 256) {
        const float v = hacc[i] + b1[i];
        hsh[i] = (v > 0.f) ? v : 0.f;
    }
    __syncthreads();
    float acc[10];
    #pragma unroll
    for (int k = 0; k < 10; ++k) acc[k] = 0.f;
    for (int i = t; i < H1; i += 256) {
        const float h = hsh[i];
        #pragma unroll
        for (int k = 0; k < 10; ++k) acc[k] = fmaf(h, W2[i * 10 + k], acc[k]);
    }
    for (int k = 0; k < 10; ++k) {
        red[t] = acc[k]; __syncthreads();
        for (int s2 = 128; s2 > 0; s2 >>= 1) {
            if (t < s2) red[t] += red[t + s2];
            __syncthreads();
        }
        if (t == 0) out[k] = red[0] + b2[k];
        __syncthreads();
    }
}

// ---------------- launch ----------------
extern "C" void kernel_launch(void* const* d_in, const int* in_sizes, int n_in,
                              void* d_out, int out_size, void* d_ws, size_t ws_size,
                              hipStream_t stream)
{
    const float* x     = (const float*)d_in[0];
    const float* Wg    = (const float*)d_in[1];
    const float* att_s = (const float*)d_in[2];
    const float* att_d = (const float*)d_in[3];
    const float* b_gat = (const float*)d_in[4];
    const float* Wgcn  = (const float*)d_in[5];
    const float* b_gcn = (const float*)d_in[6];
    const float* W1    = (const float*)d_in[7];
    const float* b1    = (const float*)d_in[8];
    const float* W2    = (const float*)d_in[9];
    const float* b2    = (const float*)d_in[10];
    const int*   ei    = (const int*)d_in[11];
    const int E = in_sizes[11] / 2;
    const int EP = E + NN;
    float* out = (float*)d_out;

    char* wsp = (char*)d_ws;
    size_t off = 0;
    auto alc = [&](size_t b) { void* p = wsp + off; off += (b + 255) & ~(size_t)255; return p; };
    _Float16* bufA = (_Float16*)alc((size_t)NN * HDIM * 2);  // xl, later xw
    _Float16* bufB = (_Float16*)alc((size_t)NN * HDIM * 2);  // x1, later x2
    float* aS     = (float*)alc((size_t)NN * HH * 4);
    float* aD     = (float*)alc((size_t)NN * HH * 4);
    float* den    = (float*)alc((size_t)NN * HH * 4);
    int*   rowptr = (int*)alc((size_t)(NN + 1) * 4);
    int*   cnt    = (int*)alc((size_t)NN * 4);
    int*   cursor = (int*)alc((size_t)NN * 4);
    int*   csr    = (int*)alc((size_t)EP * 4);
    float* dinv   = (float*)alc((size_t)NN * 4);
    float* wn     = (float*)alc((size_t)EP * 4);
    float* wgat   = (float*)alc((size_t)EP * HH * 4);        // [edge][head]
    _Float16* Wbt = (_Float16*)alc((size_t)HDIM * HDIM * 2);
    float* pmax   = (float*)alc((size_t)HDIM * 4);
    float* psum   = (float*)alc((size_t)HDIM * 4);
    float* hacc   = (float*)alc((size_t)H1 * 4);

    hipMemsetAsync(cnt,    0, (size_t)NN * 4,   stream);
    hipMemsetAsync(cursor, 0, (size_t)NN * 4,   stream);
    hipMemsetAsync(pmax,   0, (size_t)HDIM * 4, stream);
    hipMemsetAsync(psum,   0, (size_t)HDIM * 4, stream);
    hipMemsetAsync(hacc,   0, (size_t)H1 * 4,   stream);

    k_count<<<(EP + 255) / 256, 256, 0, stream>>>(ei, E, cnt);
    k_scan<<<1, 1024, 0, stream>>>(cnt, rowptr, dinv);
    k_fill<<<(EP + 255) / 256, 256, 0, stream>>>(ei, E, rowptr, cursor, csr, dinv, wn);
    dim3 gw(HDIM / 32, HDIM / 32);
    k_cvtW<<<gw, 256, 0, stream>>>(Wgcn, Wbt);
    dim3 g1((NN + 127) / 128, HH);
    k_gemm1<<<g1, 256, 0, stream>>>(x, Wg, att_s, att_d, bufA, aS, aD);
    k_stat<<<(NN * HH + 255) / 256, 256, 0, stream>>>(rowptr, csr, aS, aD, wgat, den);
    k_gat_gather<<<NN / 4, 256, 0, stream>>>(rowptr, csr, wgat, den, bufA, b_gat, bufB);
    dim3 g2((NN + 127) / 128, HDIM / 128);
    k_gemm2<<<g2, 256, 0, stream>>>(bufB, Wbt, bufA);
    k_gcn_gather<<<NN / 4, 256, 0, stream>>>(rowptr, csr, wn, bufA, b_gcn, bufB);
    dim3 gp(HDIM / 128, 80);
    k_pool<<<gp, 64, 0, stream>>>(bufB, pmax, psum);
    dim3 gm1(6, 16);
    k_mlp1<<<gm1, 256, 0, stream>>>(pmax, psum, W1, hacc);
    k_mlp2<<<1, 256, 0, stream>>>(hacc, b1, W2, b2, out);
}

// Round 6
// 429.042 us; speedup vs baseline: 2.3073x; 1.0097x over previous
//
#include <hip/hip_runtime.h>
#include <hip/hip_bf16.h>
#include <math.h>

#define NN 20000
#define DD 64
#define HH 10
#define HDIM 640
#define NEG 0.2f
#define H1 1500

typedef _Float16 half8 __attribute__((ext_vector_type(8)));
typedef _Float16 half4v __attribute__((ext_vector_type(4)));
typedef _Float16 half2v __attribute__((ext_vector_type(2)));
typedef float f32x4 __attribute__((ext_vector_type(4)));

// ---------------- GEMM1: xl(fp16) = x @ W_gat, fused a_src/a_dst via shuffle ----------------
__global__ __launch_bounds__(256) void k_gemm1(
    const float* __restrict__ x, const float* __restrict__ Wg,
    const float* __restrict__ att_s, const float* __restrict__ att_d,
    _Float16* __restrict__ xl, float* __restrict__ a_src, float* __restrict__ a_dst)
{
    __shared__ float xsT[64][132];   // [k][m], padded
    __shared__ float wsb[64][64];    // [k][n]
    const int tid = threadIdx.x;
    const int m0 = blockIdx.x * 128;
    const int h  = blockIdx.y;
    const int n0 = h * 64;

    #pragma unroll
    for (int j = 0; j < 8; ++j) {
        const int lin = tid + j * 256;
        const int mm = lin >> 4, k4 = (lin & 15) * 4;
        float4 v = {0.f, 0.f, 0.f, 0.f};
        const int row = m0 + mm;
        if (row < NN) v = *(const float4*)&x[(size_t)row * DD + k4];
        xsT[k4 + 0][mm] = v.x; xsT[k4 + 1][mm] = v.y;
        xsT[k4 + 2][mm] = v.z; xsT[k4 + 3][mm] = v.w;
    }
    #pragma unroll
    for (int j = 0; j < 4; ++j) {
        const int lin = tid + j * 256;
        const int kk = lin >> 4, n4 = (lin & 15) * 4;
        *(float4*)&wsb[kk][n4] = *(const float4*)&Wg[(size_t)kk * HDIM + n0 + n4];
    }
    __syncthreads();

    const int cid = tid & 15, rid = tid >> 4;
    const int r0 = rid * 8, cg = cid * 4;
    float acc[8][4];
    #pragma unroll
    for (int i = 0; i < 8; ++i)
        #pragma unroll
        for (int j = 0; j < 4; ++j) acc[i][j] = 0.f;

    #pragma unroll 16
    for (int k = 0; k < 64; ++k) {
        const float4 a0 = *(const float4*)&xsT[k][r0];
        const float4 a1 = *(const float4*)&xsT[k][r0 + 4];
        const float4 b  = *(const float4*)&wsb[k][cg];
        const float av[8] = {a0.x, a0.y, a0.z, a0.w, a1.x, a1.y, a1.z, a1.w};
        const float bv[4] = {b.x, b.y, b.z, b.w};
        #pragma unroll
        for (int i = 0; i < 8; ++i)
            #pragma unroll
            for (int j = 0; j < 4; ++j)
                acc[i][j] = fmaf(av[i], bv[j], acc[i][j]);
    }

    const float4 as4 = *(const float4*)&att_s[h * DD + cg];
    const float4 ad4 = *(const float4*)&att_d[h * DD + cg];
    #pragma unroll
    for (int i = 0; i < 8; ++i) {
        const int row = m0 + r0 + i;
        float ps = acc[i][0] * as4.x + acc[i][1] * as4.y + acc[i][2] * as4.z + acc[i][3] * as4.w;
        float pd = acc[i][0] * ad4.x + acc[i][1] * ad4.y + acc[i][2] * ad4.z + acc[i][3] * ad4.w;
        #pragma unroll
        for (int off = 8; off > 0; off >>= 1) {
            ps += __shfl_down(ps, off, 16);
            pd += __shfl_down(pd, off, 16);
        }
        if (row < NN) {
            half4v o = {(_Float16)acc[i][0], (_Float16)acc[i][1],
                        (_Float16)acc[i][2], (_Float16)acc[i][3]};
            *(half4v*)&xl[(size_t)row * HDIM + n0 + cg] = o;
            if (cid == 0) {
                a_src[row * HH + h] = ps;
                a_dst[row * HH + h] = pd;
            }
        }
    }
}

// ---------------- CSR build ----------------
__global__ void k_count(const int* __restrict__ ei, int E, int* __restrict__ cnt)
{
    const int e = blockIdx.x * blockDim.x + threadIdx.x;
    if (e >= E + NN) return;
    const int d = (e < E) ? ei[E + e] : (e - E);
    atomicAdd(&cnt[d], 1);
}

__global__ __launch_bounds__(1024) void k_scan(const int* __restrict__ cnt,
                                               int* __restrict__ rowptr,
                                               float* __restrict__ dinv)
{
    __shared__ int sh[1024];
    const int t = threadIdx.x;
    const int CH = 20;
    const int base = t * CH;
    int loc[CH];
    int s = 0;
    #pragma unroll
    for (int i = 0; i < CH; ++i) {
        const int idx = base + i;
        const int c = (idx < NN) ? cnt[idx] : 0;
        loc[i] = s; s += c;
    }
    sh[t] = s; __syncthreads();
    for (int off = 1; off < 1024; off <<= 1) {
        const int v = (t >= off) ? sh[t - off] : 0;
        __syncthreads();
        sh[t] += v;
        __syncthreads();
    }
    const int prev = (t == 0) ? 0 : sh[t - 1];
    #pragma unroll
    for (int i = 0; i < CH; ++i) {
        const int idx = base + i;
        if (idx < NN) {
            rowptr[idx] = prev + loc[i];
            dinv[idx]   = rsqrtf((float)cnt[idx]);
        }
    }
    if (t == 1023) rowptr[NN] = sh[1023];
}

// fill CSR + per-edge GCN symmetric norm
__global__ void k_fill(const int* __restrict__ ei, int E,
                       const int* __restrict__ rowptr,
                       int* __restrict__ cursor, int* __restrict__ csr,
                       const float* __restrict__ dinv, float* __restrict__ wn)
{
    const int e = blockIdx.x * blockDim.x + threadIdx.x;
    if (e >= E + NN) return;
    int s, d;
    if (e < E) { s = ei[e]; d = ei[E + e]; } else { s = d = e - E; }
    const int pos = atomicAdd(&cursor[d], 1);
    const int idx = rowptr[d] + pos;
    csr[idx] = s;
    wn[idx]  = dinv[s] * dinv[d];
}

// ---------------- fused GAT: softmax weights (phase A, LDS) + row gather (phase B) ----------------
// One wave per node. Tile of 64 edges: phase A lane j computes exp(leaky(alpha)) for
// all 10 heads of edge j into LDS (stride 11: odd -> conflict-free), den via shfl_xor
// butterfly. Phase B: row gather, weights read from LDS. Tile count padded to the
// block max so __syncthreads is uniform.
__global__ __launch_bounds__(256) void k_gat_gather(
    const int* __restrict__ rowptr, const int* __restrict__ csr,
    const float* __restrict__ a_src, const float* __restrict__ a_dst,
    const _Float16* __restrict__ xl, const float* __restrict__ b_gat,
    _Float16* __restrict__ x1)
{
    __shared__ float wsh[4][64 * 11];
    __shared__ int   ssh[4][64];
    __shared__ int   tsh[4];
    const int wv = threadIdx.x >> 6, lane = threadIdx.x & 63;
    const int n = blockIdx.x * 4 + wv;
    const int j0 = rowptr[n], j1 = rowptr[n + 1];
    if (lane == 0) tsh[wv] = (j1 - j0 + 63) >> 6;
    __syncthreads();
    const int Tmax = max(max(tsh[0], tsh[1]), max(tsh[2], tsh[3]));

    const int c0 = lane * 8;
    const int h0 = lane >> 3;
    const bool dual = (lane < 16);
    const int c1 = 512 + lane * 8;
    const int h1 = 8 + (lane >> 3);

    float acc0[8], acc1[8], den[10];
    #pragma unroll
    for (int i = 0; i < 8; ++i) { acc0[i] = 0.f; acc1[i] = 0.f; }
    #pragma unroll
    for (int h = 0; h < 10; ++h) den[h] = 0.f;

    float ad[10];
    #pragma unroll
    for (int h = 0; h < 10; ++h) ad[h] = a_dst[n * HH + h];   // wave-uniform broadcast

    float* __restrict__ wrow = wsh[wv];
    int*   __restrict__ srow = ssh[wv];

    for (int t = 0; t < Tmax; ++t) {
        const int base = j0 + t * 64;
        const int cnt = min(64, j1 - base);      // may be <= 0 for padded waves
        // ---- phase A: per-edge weights ----
        float e[10];
        #pragma unroll
        for (int h = 0; h < 10; ++h) e[h] = 0.f;
        if (lane < cnt) {
            const int s = csr[base + lane];
            srow[lane] = s;
            const float* asr = &a_src[s * HH];
            #pragma unroll
            for (int h = 0; h < 10; ++h) {
                float av = asr[h] + ad[h];
                av = (av >= 0.f) ? av : NEG * av;
                const float ev = __expf(av);
                e[h] = ev;
                wrow[lane * 11 + h] = ev;
            }
        }
        #pragma unroll
        for (int m = 32; m >= 1; m >>= 1)
            #pragma unroll
            for (int h = 0; h < 10; ++h)
                e[h] += __shfl_xor(e[h], m);
        #pragma unroll
        for (int h = 0; h < 10; ++h) den[h] += e[h];
        __syncthreads();
        // ---- phase B: row gather ----
        int j = 0;
        for (; j + 3 < cnt; j += 4) {
            const int sA = srow[j], sB = srow[j + 1], sC = srow[j + 2], sD = srow[j + 3];
            const float wA0 = wrow[(j + 0) * 11 + h0];
            const float wB0 = wrow[(j + 1) * 11 + h0];
            const float wC0 = wrow[(j + 2) * 11 + h0];
            const float wD0 = wrow[(j + 3) * 11 + h0];
            const half8 vA0 = *(const half8*)&xl[(size_t)sA * HDIM + c0];
            const half8 vB0 = *(const half8*)&xl[(size_t)sB * HDIM + c0];
            const half8 vC0 = *(const half8*)&xl[(size_t)sC * HDIM + c0];
            const half8 vD0 = *(const half8*)&xl[(size_t)sD * HDIM + c0];
            #pragma unroll
            for (int i = 0; i < 8; ++i) {
                acc0[i] = fmaf(wA0, (float)vA0[i], acc0[i]);
                acc0[i] = fmaf(wB0, (float)vB0[i], acc0[i]);
                acc0[i] = fmaf(wC0, (float)vC0[i], acc0[i]);
                acc0[i] = fmaf(wD0, (float)vD0[i], acc0[i]);
            }
            if (dual) {
                const float wA1 = wrow[(j + 0) * 11 + h1];
                const float wB1 = wrow[(j + 1) * 11 + h1];
                const float wC1 = wrow[(j + 2) * 11 + h1];
                const float wD1 = wrow[(j + 3) * 11 + h1];
                const half8 vA1 = *(const half8*)&xl[(size_t)sA * HDIM + c1];
                const half8 vB1 = *(const half8*)&xl[(size_t)sB * HDIM + c1];
                const half8 vC1 = *(const half8*)&xl[(size_t)sC * HDIM + c1];
                const half8 vD1 = *(const half8*)&xl[(size_t)sD * HDIM + c1];
                #pragma unroll
                for (int i = 0; i < 8; ++i) {
                    acc1[i] = fmaf(wA1, (float)vA1[i], acc1[i]);
                    acc1[i] = fmaf(wB1, (float)vB1[i], acc1[i]);
                    acc1[i] = fmaf(wC1, (float)vC1[i], acc1[i]);
                    acc1[i] = fmaf(wD1, (float)vD1[i], acc1[i]);
                }
            }
        }
        for (; j < cnt; ++j) {
            const int sA = srow[j];
            const float wA0 = wrow[j * 11 + h0];
            const half8 vA0 = *(const half8*)&xl[(size_t)sA * HDIM + c0];
            #pragma unroll
            for (int i = 0; i < 8; ++i) acc0[i] = fmaf(wA0, (float)vA0[i], acc0[i]);
            if (dual) {
                const float wA1 = wrow[j * 11 + h1];
                const half8 vA1 = *(const half8*)&xl[(size_t)sA * HDIM + c1];
                #pragma unroll
                for (int i = 0; i < 8; ++i) acc1[i] = fmaf(wA1, (float)vA1[i], acc1[i]);
            }
        }
        __syncthreads();   // protect LDS reuse next tile
    }

    // dynamic head index -> unrolled select (avoids scratch)
    float d0 = 0.f, d1 = 0.f;
    #pragma unroll
    for (int h = 0; h < 10; ++h) {
        if (h0 == h) d0 = den[h];
        if (h1 == h) d1 = den[h];
    }
    {
        const float rr = 1.f / (d0 + 1e-16f);
        const float4 ba = *(const float4*)&b_gat[c0];
        const float4 bb = *(const float4*)&b_gat[c0 + 4];
        const float bv[8] = {ba.x, ba.y, ba.z, ba.w, bb.x, bb.y, bb.z, bb.w};
        half8 o;
        #pragma unroll
        for (int i = 0; i < 8; ++i) {
            const float v = fmaf(acc0[i], rr, bv[i]);
            o[i] = (_Float16)((v > 0.f) ? v : 0.f);
        }
        *(half8*)&x1[(size_t)n * HDIM + c0] = o;
    }
    if (dual) {
        const float rr = 1.f / (d1 + 1e-16f);
        const float4 ba = *(const float4*)&b_gat[c1];
        const float4 bb = *(const float4*)&b_gat[c1 + 4];
        const float bv[8] = {ba.x, ba.y, ba.z, ba.w, bb.x, bb.y, bb.z, bb.w};
        half8 o;
        #pragma unroll
        for (int i = 0; i < 8; ++i) {
            const float v = fmaf(acc1[i], rr, bv[i]);
            o[i] = (_Float16)((v > 0.f) ? v : 0.f);
        }
        *(half8*)&x1[(size_t)n * HDIM + c1] = o;
    }
}

// ---------------- W_gcn transpose + fp16 convert ----------------
__global__ __launch_bounds__(256) void k_cvtW(const float* __restrict__ W,
                                              _Float16* __restrict__ Wbt)
{
    __shared__ float t[32][33];
    const int bx = blockIdx.x, by = blockIdx.y;
    const int lx = threadIdx.x & 31, ly = threadIdx.x >> 5;
    #pragma unroll
    for (int i = ly; i < 32; i += 8)
        t[i][lx] = W[(size_t)(by * 32 + i) * HDIM + bx * 32 + lx];
    __syncthreads();
    #pragma unroll
    for (int j = ly; j < 32; j += 8)
        Wbt[(size_t)(bx * 32 + j) * HDIM + by * 32 + lx] = (_Float16)t[lx][j];
}

// ---------------- GEMM2: xw(fp16) = x1 @ W_gcn via MFMA fp16 ----------------
__global__ __launch_bounds__(256) void k_gemm2(const _Float16* __restrict__ X,
                                               const _Float16* __restrict__ Wbt,
                                               _Float16* __restrict__ Y)
{
    __shared__ _Float16 As[128][40];
    __shared__ _Float16 Bs[128][40];
    const int tid = threadIdx.x;
    const int m0 = blockIdx.x * 128, n0 = blockIdx.y * 128;
    const int lane = tid & 63, wave = tid >> 6;
    const int l15 = lane & 15, quad = lane >> 4;

    f32x4 acc[2][8];
    #pragma unroll
    for (int r = 0; r < 2; ++r)
        #pragma unroll
        for (int c = 0; c < 8; ++c) acc[r][c] = (f32x4){0.f, 0.f, 0.f, 0.f};

    for (int kb = 0; kb < HDIM; kb += 32) {
        #pragma unroll
        for (int j = 0; j < 2; ++j) {
            const int cc = tid + j * 256;
            const int row = cc >> 2, part = cc & 3;
            const int gr = m0 + row;
            half8 v = {0, 0, 0, 0, 0, 0, 0, 0};
            if (gr < NN) v = *(const half8*)&X[(size_t)gr * HDIM + kb + part * 8];
            *(half8*)&As[row][part * 8] = v;
        }
        #pragma unroll
        for (int j = 0; j < 2; ++j) {
            const int cc = tid + j * 256;
            const int row = cc >> 2, part = cc & 3;
            *(half8*)&Bs[row][part * 8] =
                *(const half8*)&Wbt[(size_t)(n0 + row) * HDIM + kb + part * 8];
        }
        __syncthreads();
        const half8 a0 = *(const half8*)&As[wave * 32 + l15][quad * 8];
        const half8 a1 = *(const half8*)&As[wave * 32 + 16 + l15][quad * 8];
        #pragma unroll
        for (int c = 0; c < 8; ++c) {
            const half8 b = *(const half8*)&Bs[c * 16 + l15][quad * 8];
            acc[0][c] = __builtin_amdgcn_mfma_f32_16x16x32_f16(a0, b, acc[0][c], 0, 0, 0);
            acc[1][c] = __builtin_amdgcn_mfma_f32_16x16x32_f16(a1, b, acc[1][c], 0, 0, 0);
        }
        __syncthreads();
    }
    #pragma unroll
    for (int r = 0; r < 2; ++r) {
        #pragma unroll
        for (int c = 0; c < 8; ++c) {
            #pragma unroll
            for (int g = 0; g < 4; ++g) {
                const int row = m0 + wave * 32 + r * 16 + quad * 4 + g;
                if (row < NN)
                    Y[(size_t)row * HDIM + n0 + c * 16 + l15] = (_Float16)acc[r][c][g];
            }
        }
    }
}

// ---------------- GCN gather: one wave per node, aligned 16B lanes, unroll 4 ----------------
__global__ __launch_bounds__(256) void k_gcn_gather(
    const int* __restrict__ rowptr, const int* __restrict__ csr,
    const float* __restrict__ wn, const _Float16* __restrict__ xw,
    const float* __restrict__ b_gcn, _Float16* __restrict__ x2)
{
    const int wave = threadIdx.x >> 6, lane = threadIdx.x & 63;
    const int n = blockIdx.x * 4 + wave;
    const int c0 = lane * 8;
    const bool dual = (lane < 16);
    const int c1 = 512 + lane * 8;

    float acc0[8], acc1[8];
    #pragma unroll
    for (int i = 0; i < 8; ++i) { acc0[i] = 0.f; acc1[i] = 0.f; }

    const int j0 = rowptr[n], j1 = rowptr[n + 1];
    int j = j0;
    for (; j + 3 < j1; j += 4) {
        const int sA = csr[j], sB = csr[j + 1], sC = csr[j + 2], sD = csr[j + 3];
        const float wA = wn[j], wB = wn[j + 1], wC = wn[j + 2], wD = wn[j + 3];
        const half8 vA0 = *(const half8*)&xw[(size_t)sA * HDIM + c0];
        const half8 vB0 = *(const half8*)&xw[(size_t)sB * HDIM + c0];
        const half8 vC0 = *(const half8*)&xw[(size_t)sC * HDIM + c0];
        const half8 vD0 = *(const half8*)&xw[(size_t)sD * HDIM + c0];
        #pragma unroll
        for (int i = 0; i < 8; ++i) {
            acc0[i] = fmaf(wA, (float)vA0[i], acc0[i]);
            acc0[i] = fmaf(wB, (float)vB0[i], acc0[i]);
            acc0[i] = fmaf(wC, (float)vC0[i], acc0[i]);
            acc0[i] = fmaf(wD, (float)vD0[i], acc0[i]);
        }
        if (dual) {
            const half8 vA1 = *(const half8*)&xw[(size_t)sA * HDIM + c1];
            const half8 vB1 = *(const half8*)&xw[(size_t)sB * HDIM + c1];
            const half8 vC1 = *(const half8*)&xw[(size_t)sC * HDIM + c1];
            const half8 vD1 = *(const half8*)&xw[(size_t)sD * HDIM + c1];
            #pragma unroll
            for (int i = 0; i < 8; ++i) {
                acc1[i] = fmaf(wA, (float)vA1[i], acc1[i]);
                acc1[i] = fmaf(wB, (float)vB1[i], acc1[i]);
                acc1[i] = fmaf(wC, (float)vC1[i], acc1[i]);
                acc1[i] = fmaf(wD, (float)vD1[i], acc1[i]);
            }
        }
    }
    for (; j < j1; ++j) {
        const int sA = csr[j];
        const float wA = wn[j];
        const half8 vA0 = *(const half8*)&xw[(size_t)sA * HDIM + c0];
        #pragma unroll
        for (int i = 0; i < 8; ++i) acc0[i] = fmaf(wA, (float)vA0[i], acc0[i]);
        if (dual) {
            const half8 vA1 = *(const half8*)&xw[(size_t)sA * HDIM + c1];
            #pragma unroll
            for (int i = 0; i < 8; ++i) acc1[i] = fmaf(wA, (float)vA1[i], acc1[i]);
        }
    }

    {
        const float4 ba = *(const float4*)&b_gcn[c0];
        const float4 bb = *(const float4*)&b_gcn[c0 + 4];
        const float bv[8] = {ba.x, ba.y, ba.z, ba.w, bb.x, bb.y, bb.z, bb.w};
        half8 o;
        #pragma unroll
        for (int i = 0; i < 8; ++i) {
            const float v = acc0[i] + bv[i];
            o[i] = (_Float16)((v > 0.f) ? v : 0.f);
        }
        *(half8*)&x2[(size_t)n * HDIM + c0] = o;
    }
    if (dual) {
        const float4 ba = *(const float4*)&b_gcn[c1];
        const float4 bb = *(const float4*)&b_gcn[c1 + 4];
        const float bv[8] = {ba.x, ba.y, ba.z, ba.w, bb.x, bb.y, bb.z, bb.w};
        half8 o;
        #pragma unroll
        for (int i = 0; i < 8; ++i) {
            const float v = acc1[i] + bv[i];
            o[i] = (_Float16)((v > 0.f) ? v : 0.f);
        }
        *(half8*)&x2[(size_t)n * HDIM + c1] = o;
    }
}

// ---------------- pooling (x2 fp16) ----------------
__global__ __launch_bounds__(64) void k_pool(const _Float16* __restrict__ x2,
                                             float* __restrict__ pmax,
                                             float* __restrict__ psum)
{
    const int t = threadIdx.x;
    const int col = blockIdx.x * 128 + t * 2;
    const int nb = blockIdx.y;
    float mx0 = 0.f, mx1 = 0.f, s0 = 0.f, s1 = 0.f;
    const int nend = nb * 250 + 250;
    for (int n = nb * 250; n < nend; ++n) {
        const half2v v = *(const half2v*)&x2[(size_t)n * HDIM + col];
        const float v0 = (float)v.x, v1 = (float)v.y;
        mx0 = fmaxf(mx0, v0); mx1 = fmaxf(mx1, v1);
        s0 += v0; s1 += v1;
    }
    atomicMax((int*)&pmax[col],     __float_as_int(mx0));
    atomicMax((int*)&pmax[col + 1], __float_as_int(mx1));
    atomicAdd(&psum[col],     s0);
    atomicAdd(&psum[col + 1], s1);
}

// ---------------- MLP layer 1 (split-K into hacc) ----------------
__global__ __launch_bounds__(256) void k_mlp1(const float* __restrict__ pmax,
                                              const float* __restrict__ psum,
                                              const float* __restrict__ W1,
                                              float* __restrict__ hacc)
{
    __shared__ float pl[80];
    const int t = threadIdx.x;
    const int i0 = blockIdx.y * 80;
    if (t < 80) {
        const int i = i0 + t;
        pl[t] = (i < HDIM) ? pmax[i] : psum[i - HDIM] * (1.0f / NN);
    }
    __syncthreads();
    const int j = blockIdx.x * 256 + t;
    if (j >= H1) return;
    float acc = 0.f;
    #pragma unroll 8
    for (int i = 0; i < 80; ++i)
        acc = fmaf(pl[i], W1[(size_t)(i0 + i) * H1 + j], acc);
    atomicAdd(&hacc[j], acc);
}

// ---------------- MLP layer 2 ----------------
__global__ __launch_bounds__(256) void k_mlp2(const float* __restrict__ hacc,
                                              const float* __restrict__ b1,
                                              const float* __restrict__ W2,
                                              const float* __restrict__ b2,
                                              float* __restrict__ out)
{
    __shared__ float hsh[H1];
    __shared__ float red[256];
    const int t = threadIdx.x;
    for (int i = t; i < H1; i += 256) {
        const float v = hacc[i] + b1[i];
        hsh[i] = (v > 0.f) ? v : 0.f;
    }
    __syncthreads();
    float acc[10];
    #pragma unroll
    for (int k = 0; k < 10; ++k) acc[k] = 0.f;
    for (int i = t; i < H1; i += 256) {
        const float h = hsh[i];
        #pragma unroll
        for (int k = 0; k < 10; ++k) acc[k] = fmaf(h, W2[i * 10 + k], acc[k]);
    }
    for (int k = 0; k < 10; ++k) {
        red[t] = acc[k]; __syncthreads();
        for (int s2 = 128; s2 > 0; s2 >>= 1) {
            if (t < s2) red[t] += red[t + s2];
            __syncthreads();
        }
        if (t == 0) out[k] = red[0] + b2[k];
        __syncthreads();
    }
}

// ---------------- launch ----------------
extern "C" void kernel_launch(void* const* d_in, const int* in_sizes, int n_in,
                              void* d_out, int out_size, void* d_ws, size_t ws_size,
                              hipStream_t stream)
{
    const float* x     = (const float*)d_in[0];
    const float* Wg    = (const float*)d_in[1];
    const float* att_s = (const float*)d_in[2];
    const float* att_d = (const float*)d_in[3];
    const float* b_gat = (const float*)d_in[4];
    const float* Wgcn  = (const float*)d_in[5];
    const float* b_gcn = (const float*)d_in[6];
    const float* W1    = (const float*)d_in[7];
    const float* b1    = (const float*)d_in[8];
    const float* W2    = (const float*)d_in[9];
    const float* b2    = (const float*)d_in[10];
    const int*   ei    = (const int*)d_in[11];
    const int E = in_sizes[11] / 2;
    const int EP = E + NN;
    float* out = (float*)d_out;

    char* wsp = (char*)d_ws;
    size_t off = 0;
    auto alc = [&](size_t b) { void* p = wsp + off; off += (b + 255) & ~(size_t)255; return p; };
    _Float16* bufA = (_Float16*)alc((size_t)NN * HDIM * 2);  // xl, later xw
    _Float16* bufB = (_Float16*)alc((size_t)NN * HDIM * 2);  // x1, later x2
    float* aS     = (float*)alc((size_t)NN * HH * 4);
    float* aD     = (float*)alc((size_t)NN * HH * 4);
    int*   rowptr = (int*)alc((size_t)(NN + 1) * 4);
    int*   csr    = (int*)alc((size_t)EP * 4);
    float* dinv   = (float*)alc((size_t)NN * 4);
    float* wn     = (float*)alc((size_t)EP * 4);
    _Float16* Wbt = (_Float16*)alc((size_t)HDIM * HDIM * 2);
    // zero-initialized region (single memset): cnt | cursor | pmax | psum | hacc
    const size_t zoff = off;
    int*   cnt    = (int*)alc((size_t)NN * 4);
    int*   cursor = (int*)alc((size_t)NN * 4);
    float* pmax   = (float*)alc((size_t)HDIM * 4);
    float* psum   = (float*)alc((size_t)HDIM * 4);
    float* hacc   = (float*)alc((size_t)H1 * 4);
    const size_t zsize = off - zoff;

    hipMemsetAsync(cnt, 0, zsize, stream);

    k_count<<<(EP + 255) / 256, 256, 0, stream>>>(ei, E, cnt);
    k_scan<<<1, 1024, 0, stream>>>(cnt, rowptr, dinv);
    k_fill<<<(EP + 255) / 256, 256, 0, stream>>>(ei, E, rowptr, cursor, csr, dinv, wn);
    dim3 gw(HDIM / 32, HDIM / 32);
    k_cvtW<<<gw, 256, 0, stream>>>(Wgcn, Wbt);
    dim3 g1((NN + 127) / 128, HH);
    k_gemm1<<<g1, 256, 0, stream>>>(x, Wg, att_s, att_d, bufA, aS, aD);
    k_gat_gather<<<NN / 4, 256, 0, stream>>>(rowptr, csr, aS, aD, bufA, b_gat, bufB);
    dim3 g2((NN + 127) / 128, HDIM / 128);
    k_gemm2<<<g2, 256, 0, stream>>>(bufB, Wbt, bufA);
    k_gcn_gather<<<NN / 4, 256, 0, stream>>>(rowptr, csr, wn, bufA, b_gcn, bufB);
    dim3 gp(HDIM / 128, 80);
    k_pool<<<gp, 64, 0, stream>>>(bufB, pmax, psum);
    dim3 gm1(6, 16);
    k_mlp1<<<gm1, 256, 0, stream>>>(pmax, psum, W1, hacc);
    k_mlp2<<<1, 256, 0, stream>>>(hacc, b1, W2, b2, out);
}

// Round 7
// 403.678 us; speedup vs baseline: 2.4523x; 1.0628x over previous
//
#include <hip/hip_runtime.h>
#include <hip/hip_bf16.h>
#include <math.h>

#define NN 20000
#define DD 64
#define HH 10
#define HDIM 640
#define NEG 0.2f
#define H1 1500
#define ASTRIDE 12   // a_src/a_dst row stride (floats): 48B, 16B-aligned

typedef _Float16 half8 __attribute__((ext_vector_type(8)));
typedef _Float16 half4v __attribute__((ext_vector_type(4)));
typedef _Float16 half2v __attribute__((ext_vector_type(2)));
typedef float f32x4 __attribute__((ext_vector_type(4)));

// ---------------- generic transpose + fp16 convert: WT[c][r] = W[r][c] ----------------
__global__ __launch_bounds__(256) void k_cvtT(const float* __restrict__ W,
                                              _Float16* __restrict__ WT,
                                              int rows, int cols)
{
    __shared__ float t[32][33];
    const int bx = blockIdx.x, by = blockIdx.y;   // bx: col-tile, by: row-tile
    const int lx = threadIdx.x & 31, ly = threadIdx.x >> 5;
    #pragma unroll
    for (int i = ly; i < 32; i += 8)
        t[i][lx] = W[(size_t)(by * 32 + i) * cols + bx * 32 + lx];
    __syncthreads();
    #pragma unroll
    for (int j = ly; j < 32; j += 8)
        WT[(size_t)(bx * 32 + j) * rows + by * 32 + lx] = (_Float16)t[lx][j];
}

// ---------------- GEMM1 (MFMA fp16): xl = x @ W_gat, fused a_src/a_dst dots ----------------
// M-tile 128, N-tile 64 (= one head), K = 64 staged once. 4 waves x (2x4) 16x16 tiles.
__global__ __launch_bounds__(256) void k_gemm1(
    const float* __restrict__ x, const _Float16* __restrict__ WgT,
    const float* __restrict__ att_s, const float* __restrict__ att_d,
    _Float16* __restrict__ xl, float* __restrict__ a_src, float* __restrict__ a_dst)
{
    __shared__ _Float16 As[128][72];   // [m][k], 144B stride (16B-aligned rows)
    __shared__ _Float16 Bs[64][72];    // [n][k]
    const int tid = threadIdx.x;
    const int m0 = blockIdx.x * 128;
    const int h  = blockIdx.y;
    const int n0 = h * 64;

    // stage x tile (fp32 -> fp16): thread -> (row, 32-col half)
    {
        const int row = tid >> 1, ch = (tid & 1) * 32;
        const int gr = m0 + row;
        if (gr < NN) {
            const float* xp = &x[(size_t)gr * DD + ch];
            #pragma unroll
            for (int i = 0; i < 8; ++i) {
                const float4 v = *(const float4*)&xp[i * 4];
                half4v o = {(_Float16)v.x, (_Float16)v.y, (_Float16)v.z, (_Float16)v.w};
                *(half4v*)&As[row][ch + i * 4] = o;
            }
        } else {
            const half8 z = {0, 0, 0, 0, 0, 0, 0, 0};
            #pragma unroll
            for (int i = 0; i < 4; ++i) *(half8*)&As[row][ch + i * 8] = z;
        }
    }
    // stage WgT tile: rows n0..n0+63, 64 k each
    {
        const int row = tid >> 2, part = (tid & 3) * 16;
        const _Float16* wp = &WgT[(size_t)(n0 + row) * DD + part];
        *(half8*)&Bs[row][part]     = *(const half8*)&wp[0];
        *(half8*)&Bs[row][part + 8] = *(const half8*)&wp[8];
    }
    __syncthreads();

    const int lane = tid & 63, wave = tid >> 6;
    const int l15 = lane & 15, quad = lane >> 4;
    f32x4 acc[2][4];
    #pragma unroll
    for (int r = 0; r < 2; ++r)
        #pragma unroll
        for (int c = 0; c < 4; ++c) acc[r][c] = (f32x4){0.f, 0.f, 0.f, 0.f};

    #pragma unroll
    for (int ks = 0; ks < 2; ++ks) {
        const half8 a0 = *(const half8*)&As[wave * 32 + l15][ks * 32 + quad * 8];
        const half8 a1 = *(const half8*)&As[wave * 32 + 16 + l15][ks * 32 + quad * 8];
        #pragma unroll
        for (int c = 0; c < 4; ++c) {
            const half8 b = *(const half8*)&Bs[c * 16 + l15][ks * 32 + quad * 8];
            acc[0][c] = __builtin_amdgcn_mfma_f32_16x16x32_f16(a0, b, acc[0][c], 0, 0, 0);
            acc[1][c] = __builtin_amdgcn_mfma_f32_16x16x32_f16(a1, b, acc[1][c], 0, 0, 0);
        }
    }

    float asv[4], adv[4];
    #pragma unroll
    for (int c = 0; c < 4; ++c) {
        asv[c] = att_s[h * DD + c * 16 + l15];
        adv[c] = att_d[h * DD + c * 16 + l15];
    }
    #pragma unroll
    for (int r = 0; r < 2; ++r) {
        float ps[4] = {0.f, 0.f, 0.f, 0.f}, pd[4] = {0.f, 0.f, 0.f, 0.f};
        #pragma unroll
        for (int c = 0; c < 4; ++c)
            #pragma unroll
            for (int g = 0; g < 4; ++g) {
                ps[g] = fmaf(acc[r][c][g], asv[c], ps[g]);
                pd[g] = fmaf(acc[r][c][g], adv[c], pd[g]);
            }
        #pragma unroll
        for (int m = 1; m <= 8; m <<= 1)
            #pragma unroll
            for (int g = 0; g < 4; ++g) {
                ps[g] += __shfl_xor(ps[g], m);
                pd[g] += __shfl_xor(pd[g], m);
            }
        #pragma unroll
        for (int c = 0; c < 4; ++c)
            #pragma unroll
            for (int g = 0; g < 4; ++g) {
                const int row = m0 + wave * 32 + r * 16 + quad * 4 + g;
                if (row < NN)
                    xl[(size_t)row * HDIM + n0 + c * 16 + l15] = (_Float16)acc[r][c][g];
            }
        if (l15 == 0)
            #pragma unroll
            for (int g = 0; g < 4; ++g) {
                const int row = m0 + wave * 32 + r * 16 + quad * 4 + g;
                if (row < NN) {
                    a_src[(size_t)row * ASTRIDE + h] = ps[g];
                    a_dst[(size_t)row * ASTRIDE + h] = pd[g];
                }
            }
    }
}

// ---------------- CSR build ----------------
__global__ void k_count(const int* __restrict__ ei, int E, int* __restrict__ cnt)
{
    const int e = blockIdx.x * blockDim.x + threadIdx.x;
    if (e >= E + NN) return;
    const int d = (e < E) ? ei[E + e] : (e - E);
    atomicAdd(&cnt[d], 1);
}

__global__ __launch_bounds__(1024) void k_scan(const int* __restrict__ cnt,
                                               int* __restrict__ rowptr,
                                               float* __restrict__ dinv)
{
    __shared__ int sh[1024];
    const int t = threadIdx.x;
    const int CH = 20;
    const int base = t * CH;
    int loc[CH];
    int s = 0;
    #pragma unroll
    for (int i = 0; i < CH; ++i) {
        const int idx = base + i;
        const int c = (idx < NN) ? cnt[idx] : 0;
        loc[i] = s; s += c;
    }
    sh[t] = s; __syncthreads();
    for (int off = 1; off < 1024; off <<= 1) {
        const int v = (t >= off) ? sh[t - off] : 0;
        __syncthreads();
        sh[t] += v;
        __syncthreads();
    }
    const int prev = (t == 0) ? 0 : sh[t - 1];
    #pragma unroll
    for (int i = 0; i < CH; ++i) {
        const int idx = base + i;
        if (idx < NN) {
            rowptr[idx] = prev + loc[i];
            dinv[idx]   = rsqrtf((float)cnt[idx]);
        }
    }
    if (t == 1023) rowptr[NN] = sh[1023];
}

// fill CSR + per-edge dst + GCN symmetric norm
__global__ void k_fill(const int* __restrict__ ei, int E,
                       const int* __restrict__ rowptr,
                       int* __restrict__ cursor, int* __restrict__ csr,
                       int* __restrict__ dstv,
                       const float* __restrict__ dinv, float* __restrict__ wn)
{
    const int e = blockIdx.x * blockDim.x + threadIdx.x;
    if (e >= E + NN) return;
    int s, d;
    if (e < E) { s = ei[e]; d = ei[E + e]; } else { s = d = e - E; }
    const int pos = atomicAdd(&cursor[d], 1);
    const int idx = rowptr[d] + pos;
    csr[idx]  = s;
    dstv[idx] = d;
    wn[idx]   = dinv[s] * dinv[d];
}

// ---------------- edge-parallel: wgat[e][h] = exp(leaky(a_src[s]+a_dst[d])) ----------------
__global__ void k_stat(const int* __restrict__ csr, const int* __restrict__ dstv,
                       const float* __restrict__ aS, const float* __restrict__ aD,
                       float* __restrict__ wgat, int EP)
{
    const int j = blockIdx.x * blockDim.x + threadIdx.x;
    if (j >= EP) return;
    const int s = csr[j], d = dstv[j];
    const f32x4 s0 = *(const f32x4*)&aS[(size_t)s * ASTRIDE];
    const f32x4 s1 = *(const f32x4*)&aS[(size_t)s * ASTRIDE + 4];
    const float2 s2 = *(const float2*)&aS[(size_t)s * ASTRIDE + 8];
    const f32x4 d0 = *(const f32x4*)&aD[(size_t)d * ASTRIDE];
    const f32x4 d1 = *(const f32x4*)&aD[(size_t)d * ASTRIDE + 4];
    const float2 d2 = *(const float2*)&aD[(size_t)d * ASTRIDE + 8];
    const float av[10] = {s0.x + d0.x, s0.y + d0.y, s0.z + d0.z, s0.w + d0.w,
                          s1.x + d1.x, s1.y + d1.y, s1.z + d1.z, s1.w + d1.w,
                          s2.x + d2.x, s2.y + d2.y};
    float* wp = &wgat[(size_t)j * HH];
    #pragma unroll
    for (int h = 0; h < 10; ++h) {
        float a = av[h];
        a = (a >= 0.f) ? a : NEG * a;
        wp[h] = __expf(a);
    }
}

// ---------------- GAT gather: wave per node, den accumulated in-flight ----------------
__global__ __launch_bounds__(256) void k_gat_gather(
    const int* __restrict__ rowptr, const int* __restrict__ csr,
    const float* __restrict__ wgat, const _Float16* __restrict__ xl,
    const float* __restrict__ b_gat, _Float16* __restrict__ x1)
{
    const int wave = threadIdx.x >> 6, lane = threadIdx.x & 63;
    const int n = blockIdx.x * 4 + wave;
    const int c0 = lane * 8;
    const int h0 = lane >> 3;
    const bool dual = (lane < 16);
    const int c1 = 512 + lane * 8;
    const int h1 = 8 + (lane >> 3);

    float acc0[8], acc1[8], ws0 = 0.f, ws1 = 0.f;
    #pragma unroll
    for (int i = 0; i < 8; ++i) { acc0[i] = 0.f; acc1[i] = 0.f; }

    const int j0 = rowptr[n], j1 = rowptr[n + 1];
    int j = j0;
    for (; j + 3 < j1; j += 4) {
        const int sA = csr[j], sB = csr[j + 1], sC = csr[j + 2], sD = csr[j + 3];
        const float wA0 = wgat[(size_t)(j + 0) * HH + h0];
        const float wB0 = wgat[(size_t)(j + 1) * HH + h0];
        const float wC0 = wgat[(size_t)(j + 2) * HH + h0];
        const float wD0 = wgat[(size_t)(j + 3) * HH + h0];
        ws0 += wA0 + wB0 + wC0 + wD0;
        const half8 vA0 = *(const half8*)&xl[(size_t)sA * HDIM + c0];
        const half8 vB0 = *(const half8*)&xl[(size_t)sB * HDIM + c0];
        const half8 vC0 = *(const half8*)&xl[(size_t)sC * HDIM + c0];
        const half8 vD0 = *(const half8*)&xl[(size_t)sD * HDIM + c0];
        #pragma unroll
        for (int i = 0; i < 8; ++i) {
            acc0[i] = fmaf(wA0, (float)vA0[i], acc0[i]);
            acc0[i] = fmaf(wB0, (float)vB0[i], acc0[i]);
            acc0[i] = fmaf(wC0, (float)vC0[i], acc0[i]);
            acc0[i] = fmaf(wD0, (float)vD0[i], acc0[i]);
        }
        if (dual) {
            const float wA1 = wgat[(size_t)(j + 0) * HH + h1];
            const float wB1 = wgat[(size_t)(j + 1) * HH + h1];
            const float wC1 = wgat[(size_t)(j + 2) * HH + h1];
            const float wD1 = wgat[(size_t)(j + 3) * HH + h1];
            ws1 += wA1 + wB1 + wC1 + wD1;
            const half8 vA1 = *(const half8*)&xl[(size_t)sA * HDIM + c1];
            const half8 vB1 = *(const half8*)&xl[(size_t)sB * HDIM + c1];
            const half8 vC1 = *(const half8*)&xl[(size_t)sC * HDIM + c1];
            const half8 vD1 = *(const half8*)&xl[(size_t)sD * HDIM + c1];
            #pragma unroll
            for (int i = 0; i < 8; ++i) {
                acc1[i] = fmaf(wA1, (float)vA1[i], acc1[i]);
                acc1[i] = fmaf(wB1, (float)vB1[i], acc1[i]);
                acc1[i] = fmaf(wC1, (float)vC1[i], acc1[i]);
                acc1[i] = fmaf(wD1, (float)vD1[i], acc1[i]);
            }
        }
    }
    for (; j < j1; ++j) {
        const int sA = csr[j];
        const float wA0 = wgat[(size_t)j * HH + h0];
        ws0 += wA0;
        const half8 vA0 = *(const half8*)&xl[(size_t)sA * HDIM + c0];
        #pragma unroll
        for (int i = 0; i < 8; ++i) acc0[i] = fmaf(wA0, (float)vA0[i], acc0[i]);
        if (dual) {
            const float wA1 = wgat[(size_t)j * HH + h1];
            ws1 += wA1;
            const half8 vA1 = *(const half8*)&xl[(size_t)sA * HDIM + c1];
            #pragma unroll
            for (int i = 0; i < 8; ++i) acc1[i] = fmaf(wA1, (float)vA1[i], acc1[i]);
        }
    }

    {
        const float rr = 1.f / (ws0 + 1e-16f);
        const float4 ba = *(const float4*)&b_gat[c0];
        const float4 bb = *(const float4*)&b_gat[c0 + 4];
        const float bv[8] = {ba.x, ba.y, ba.z, ba.w, bb.x, bb.y, bb.z, bb.w};
        half8 o;
        #pragma unroll
        for (int i = 0; i < 8; ++i) {
            const float v = fmaf(acc0[i], rr, bv[i]);
            o[i] = (_Float16)((v > 0.f) ? v : 0.f);
        }
        *(half8*)&x1[(size_t)n * HDIM + c0] = o;
    }
    if (dual) {
        const float rr = 1.f / (ws1 + 1e-16f);
        const float4 ba = *(const float4*)&b_gat[c1];
        const float4 bb = *(const float4*)&b_gat[c1 + 4];
        const float bv[8] = {ba.x, ba.y, ba.z, ba.w, bb.x, bb.y, bb.z, bb.w};
        half8 o;
        #pragma unroll
        for (int i = 0; i < 8; ++i) {
            const float v = fmaf(acc1[i], rr, bv[i]);
            o[i] = (_Float16)((v > 0.f) ? v : 0.f);
        }
        *(half8*)&x1[(size_t)n * HDIM + c1] = o;
    }
}

// ---------------- GEMM2: xw(fp16) = x1 @ W_gcn via MFMA fp16 ----------------
__global__ __launch_bounds__(256) void k_gemm2(const _Float16* __restrict__ X,
                                               const _Float16* __restrict__ Wbt,
                                               _Float16* __restrict__ Y)
{
    __shared__ _Float16 As[128][40];
    __shared__ _Float16 Bs[128][40];
    const int tid = threadIdx.x;
    const int m0 = blockIdx.x * 128, n0 = blockIdx.y * 128;
    const int lane = tid & 63, wave = tid >> 6;
    const int l15 = lane & 15, quad = lane >> 4;

    f32x4 acc[2][8];
    #pragma unroll
    for (int r = 0; r < 2; ++r)
        #pragma unroll
        for (int c = 0; c < 8; ++c) acc[r][c] = (f32x4){0.f, 0.f, 0.f, 0.f};

    for (int kb = 0; kb < HDIM; kb += 32) {
        #pragma unroll
        for (int j = 0; j < 2; ++j) {
            const int cc = tid + j * 256;
            const int row = cc >> 2, part = cc & 3;
            const int gr = m0 + row;
            half8 v = {0, 0, 0, 0, 0, 0, 0, 0};
            if (gr < NN) v = *(const half8*)&X[(size_t)gr * HDIM + kb + part * 8];
            *(half8*)&As[row][part * 8] = v;
        }
        #pragma unroll
        for (int j = 0; j < 2; ++j) {
            const int cc = tid + j * 256;
            const int row = cc >> 2, part = cc & 3;
            *(half8*)&Bs[row][part * 8] =
                *(const half8*)&Wbt[(size_t)(n0 + row) * HDIM + kb + part * 8];
        }
        __syncthreads();
        const half8 a0 = *(const half8*)&As[wave * 32 + l15][quad * 8];
        const half8 a1 = *(const half8*)&As[wave * 32 + 16 + l15][quad * 8];
        #pragma unroll
        for (int c = 0; c < 8; ++c) {
            const half8 b = *(const half8*)&Bs[c * 16 + l15][quad * 8];
            acc[0][c] = __builtin_amdgcn_mfma_f32_16x16x32_f16(a0, b, acc[0][c], 0, 0, 0);
            acc[1][c] = __builtin_amdgcn_mfma_f32_16x16x32_f16(a1, b, acc[1][c], 0, 0, 0);
        }
        __syncthreads();
    }
    #pragma unroll
    for (int r = 0; r < 2; ++r) {
        #pragma unroll
        for (int c = 0; c < 8; ++c) {
            #pragma unroll
            for (int g = 0; g < 4; ++g) {
                const int row = m0 + wave * 32 + r * 16 + quad * 4 + g;
                if (row < NN)
                    Y[(size_t)row * HDIM + n0 + c * 16 + l15] = (_Float16)acc[r][c][g];
            }
        }
    }
}

// ---------------- GCN gather: wave per node, unroll 4 ----------------
__global__ __launch_bounds__(256) void k_gcn_gather(
    const int* __restrict__ rowptr, const int* __restrict__ csr,
    const float* __restrict__ wn, const _Float16* __restrict__ xw,
    const float* __restrict__ b_gcn, _Float16* __restrict__ x2)
{
    const int wave = threadIdx.x >> 6, lane = threadIdx.x & 63;
    const int n = blockIdx.x * 4 + wave;
    const int c0 = lane * 8;
    const bool dual = (lane < 16);
    const int c1 = 512 + lane * 8;

    float acc0[8], acc1[8];
    #pragma unroll
    for (int i = 0; i < 8; ++i) { acc0[i] = 0.f; acc1[i] = 0.f; }

    const int j0 = rowptr[n], j1 = rowptr[n + 1];
    int j = j0;
    for (; j + 3 < j1; j += 4) {
        const int sA = csr[j], sB = csr[j + 1], sC = csr[j + 2], sD = csr[j + 3];
        const float wA = wn[j], wB = wn[j + 1], wC = wn[j + 2], wD = wn[j + 3];
        const half8 vA0 = *(const half8*)&xw[(size_t)sA * HDIM + c0];
        const half8 vB0 = *(const half8*)&xw[(size_t)sB * HDIM + c0];
        const half8 vC0 = *(const half8*)&xw[(size_t)sC * HDIM + c0];
        const half8 vD0 = *(const half8*)&xw[(size_t)sD * HDIM + c0];
        #pragma unroll
        for (int i = 0; i < 8; ++i) {
            acc0[i] = fmaf(wA, (float)vA0[i], acc0[i]);
            acc0[i] = fmaf(wB, (float)vB0[i], acc0[i]);
            acc0[i] = fmaf(wC, (float)vC0[i], acc0[i]);
            acc0[i] = fmaf(wD, (float)vD0[i], acc0[i]);
        }
        if (dual) {
            const half8 vA1 = *(const half8*)&xw[(size_t)sA * HDIM + c1];
            const half8 vB1 = *(const half8*)&xw[(size_t)sB * HDIM + c1];
            const half8 vC1 = *(const half8*)&xw[(size_t)sC * HDIM + c1];
            const half8 vD1 = *(const half8*)&xw[(size_t)sD * HDIM + c1];
            #pragma unroll
            for (int i = 0; i < 8; ++i) {
                acc1[i] = fmaf(wA, (float)vA1[i], acc1[i]);
                acc1[i] = fmaf(wB, (float)vB1[i], acc1[i]);
                acc1[i] = fmaf(wC, (float)vC1[i], acc1[i]);
                acc1[i] = fmaf(wD, (float)vD1[i], acc1[i]);
            }
        }
    }
    for (; j < j1; ++j) {
        const int sA = csr[j];
        const float wA = wn[j];
        const half8 vA0 = *(const half8*)&xw[(size_t)sA * HDIM + c0];
        #pragma unroll
        for (int i = 0; i < 8; ++i) acc0[i] = fmaf(wA, (float)vA0[i], acc0[i]);
        if (dual) {
            const half8 vA1 = *(const half8*)&xw[(size_t)sA * HDIM + c1];
            #pragma unroll
            for (int i = 0; i < 8; ++i) acc1[i] = fmaf(wA, (float)vA1[i], acc1[i]);
        }
    }

    {
        const float4 ba = *(const float4*)&b_gcn[c0];
        const float4 bb = *(const float4*)&b_gcn[c0 + 4];
        const float bv[8] = {ba.x, ba.y, ba.z, ba.w, bb.x, bb.y, bb.z, bb.w};
        half8 o;
        #pragma unroll
        for (int i = 0; i < 8; ++i) {
            const float v = acc0[i] + bv[i];
            o[i] = (_Float16)((v > 0.f) ? v : 0.f);
        }
        *(half8*)&x2[(size_t)n * HDIM + c0] = o;
    }
    if (dual) {
        const float4 ba = *(const float4*)&b_gcn[c1];
        const float4 bb = *(const float4*)&b_gcn[c1 + 4];
        const float bv[8] = {ba.x, ba.y, ba.z, ba.w, bb.x, bb.y, bb.z, bb.w};
        half8 o;
        #pragma unroll
        for (int i = 0; i < 8; ++i) {
            const float v = acc1[i] + bv[i];
            o[i] = (_Float16)((v > 0.f) ? v : 0.f);
        }
        *(half8*)&x2[(size_t)n * HDIM + c1] = o;
    }
}

// ---------------- pooling (x2 fp16) ----------------
__global__ __launch_bounds__(64) void k_pool(const _Float16* __restrict__ x2,
                                             float* __restrict__ pmax,
                                             float* __restrict__ psum)
{
    const int t = threadIdx.x;
    const int col = blockIdx.x * 128 + t * 2;
    const int nb = blockIdx.y;
    float mx0 = 0.f, mx1 = 0.f, s0 = 0.f, s1 = 0.f;
    const int nend = nb * 250 + 250;
    for (int n = nb * 250; n < nend; ++n) {
        const half2v v = *(const half2v*)&x2[(size_t)n * HDIM + col];
        const float v0 = (float)v.x, v1 = (float)v.y;
        mx0 = fmaxf(mx0, v0); mx1 = fmaxf(mx1, v1);
        s0 += v0; s1 += v1;
    }
    atomicMax((int*)&pmax[col],     __float_as_int(mx0));
    atomicMax((int*)&pmax[col + 1], __float_as_int(mx1));
    atomicAdd(&psum[col],     s0);
    atomicAdd(&psum[col + 1], s1);
}

// ---------------- MLP layer 1 (split-K into hacc) ----------------
__global__ __launch_bounds__(256) void k_mlp1(const float* __restrict__ pmax,
                                              const float* __restrict__ psum,
                                              const float* __restrict__ W1,
                                              float* __restrict__ hacc)
{
    __shared__ float pl[80];
    const int t = threadIdx.x;
    const int i0 = blockIdx.y * 80;
    if (t < 80) {
        const int i = i0 + t;
        pl[t] = (i < HDIM) ? pmax[i] : psum[i - HDIM] * (1.0f / NN);
    }
    __syncthreads();
    const int j = blockIdx.x * 256 + t;
    if (j >= H1) return;
    float acc = 0.f;
    #pragma unroll 8
    for (int i = 0; i < 80; ++i)
        acc = fmaf(pl[i], W1[(size_t)(i0 + i) * H1 + j], acc);
    atomicAdd(&hacc[j], acc);
}

// ---------------- MLP layer 2 ----------------
__global__ __launch_bounds__(256) void k_mlp2(const float* __restrict__ hacc,
                                              const float* __restrict__ b1,
                                              const float* __restrict__ W2,
                                              const float* __restrict__ b2,
                                              float* __restrict__ out)
{
    __shared__ float hsh[H1];
    __shared__ float red[256];
    const int t = threadIdx.x;
    for (int i = t; i < H1; i += 256) {
        const float v = hacc[i] + b1[i];
        hsh[i] = (v > 0.f) ? v : 0.f;
    }
    __syncthreads();
    float acc[10];
    #pragma unroll
    for (int k = 0; k < 10; ++k) acc[k] = 0.f;
    for (int i = t; i < H1; i += 256) {
        const float h = hsh[i];
        #pragma unroll
        for (int k = 0; k < 10; ++k) acc[k] = fmaf(h, W2[i * 10 + k], acc[k]);
    }
    for (int k = 0; k < 10; ++k) {
        red[t] = acc[k]; __syncthreads();
        for (int s2 = 128; s2 > 0; s2 >>= 1) {
            if (t < s2) red[t] += red[t + s2];
            __syncthreads();
        }
        if (t == 0) out[k] = red[0] + b2[k];
        __syncthreads();
    }
}

// ---------------- launch ----------------
extern "C" void kernel_launch(void* const* d_in, const int* in_sizes, int n_in,
                              void* d_out, int out_size, void* d_ws, size_t ws_size,
                              hipStream_t stream)
{
    const float* x     = (const float*)d_in[0];
    const float* Wg    = (const float*)d_in[1];
    const float* att_s = (const float*)d_in[2];
    const float* att_d = (const float*)d_in[3];
    const float* b_gat = (const float*)d_in[4];
    const float* Wgcn  = (const float*)d_in[5];
    const float* b_gcn = (const float*)d_in[6];
    const float* W1    = (const float*)d_in[7];
    const float* b1    = (const float*)d_in[8];
    const float* W2    = (const float*)d_in[9];
    const float* b2    = (const float*)d_in[10];
    const int*   ei    = (const int*)d_in[11];
    const int E = in_sizes[11] / 2;
    const int EP = E + NN;
    float* out = (float*)d_out;

    char* wsp = (char*)d_ws;
    size_t off = 0;
    auto alc = [&](size_t b) { void* p = wsp + off; off += (b + 255) & ~(size_t)255; return p; };
    _Float16* bufA = (_Float16*)alc((size_t)NN * HDIM * 2);  // xl, later xw
    _Float16* bufB = (_Float16*)alc((size_t)NN * HDIM * 2);  // x1, later x2
    float* aS     = (float*)alc((size_t)NN * ASTRIDE * 4);
    float* aD     = (float*)alc((size_t)NN * ASTRIDE * 4);
    int*   rowptr = (int*)alc((size_t)(NN + 1) * 4);
    int*   csr    = (int*)alc((size_t)EP * 4);
    int*   dstv   = (int*)alc((size_t)EP * 4);
    float* dinv   = (float*)alc((size_t)NN * 4);
    float* wn     = (float*)alc((size_t)EP * 4);
    float* wgat   = (float*)alc((size_t)EP * HH * 4);        // [edge][head]
    _Float16* Wbt = (_Float16*)alc((size_t)HDIM * HDIM * 2); // W_gcn^T fp16
    _Float16* WgT = (_Float16*)alc((size_t)HDIM * DD * 2);   // W_gat^T fp16 [640][64]
    // zero-initialized region (single memset): cnt | cursor | pmax | psum | hacc
    const size_t zoff = off;
    int*   cnt    = (int*)alc((size_t)NN * 4);
    int*   cursor = (int*)alc((size_t)NN * 4);
    float* pmax   = (float*)alc((size_t)HDIM * 4);
    float* psum   = (float*)alc((size_t)HDIM * 4);
    float* hacc   = (float*)alc((size_t)H1 * 4);
    const size_t zsize = off - zoff;

    hipMemsetAsync(cnt, 0, zsize, stream);

    k_count<<<(EP + 255) / 256, 256, 0, stream>>>(ei, E, cnt);
    k_scan<<<1, 1024, 0, stream>>>(cnt, rowptr, dinv);
    k_fill<<<(EP + 255) / 256, 256, 0, stream>>>(ei, E, rowptr, cursor, csr, dstv, dinv, wn);
    dim3 gw1(HDIM / 32, HDIM / 32);
    k_cvtT<<<gw1, 256, 0, stream>>>(Wgcn, Wbt, HDIM, HDIM);
    dim3 gw2(HDIM / 32, DD / 32);
    k_cvtT<<<gw2, 256, 0, stream>>>(Wg, WgT, DD, HDIM);
    dim3 g1((NN + 127) / 128, HH);
    k_gemm1<<<g1, 256, 0, stream>>>(x, WgT, att_s, att_d, bufA, aS, aD);
    k_stat<<<(EP + 255) / 256, 256, 0, stream>>>(csr, dstv, aS, aD, wgat, EP);
    k_gat_gather<<<NN / 4, 256, 0, stream>>>(rowptr, csr, wgat, bufA, b_gat, bufB);
    dim3 g2((NN + 127) / 128, HDIM / 128);
    k_gemm2<<<g2, 256, 0, stream>>>(bufB, Wbt, bufA);
    k_gcn_gather<<<NN / 4, 256, 0, stream>>>(rowptr, csr, wn, bufA, b_gcn, bufB);
    dim3 gp(HDIM / 128, 80);
    k_pool<<<gp, 64, 0, stream>>>(bufB, pmax, psum);
    dim3 gm1(6, 16);
    k_mlp1<<<gm1, 256, 0, stream>>>(pmax, psum, W1, hacc);
    k_mlp2<<<1, 256, 0, stream>>>(hacc, b1, W2, b2, out);
}